// Round 1
// baseline (255.912 us; speedup 1.0000x reference)
//
#include <hip/hip_runtime.h>

typedef _Float16 f16;
typedef _Float16 f16x4 __attribute__((ext_vector_type(4)));
typedef _Float16 f16x8 __attribute__((ext_vector_type(8)));
typedef float f32x4 __attribute__((ext_vector_type(4)));

#define MFMA16(a, b, c) __builtin_amdgcn_mfma_f32_16x16x32_f16(a, b, c, 0, 0, 0)
#define LOG2E 1.44269504f

// ---------------------------------------------------------------- cvt fp32->fp16
__global__ void cvt_f32_f16(const float* __restrict__ src, f16* __restrict__ dst, int n4) {
    int i = blockIdx.x * blockDim.x + threadIdx.x;
    if (i < n4) {
        float4 v = reinterpret_cast<const float4*>(src)[i];
        f16x4 o = { (f16)v.x, (f16)v.y, (f16)v.z, (f16)v.w };
        reinterpret_cast<f16x4*>(dst)[i] = o;
    }
}

// ---------------------------------------------------------------- GEMM C = A @ B^T
// A [M][K] f16 row-major, B [N][K] f16 row-major (i.e. weight layout), K mult of 32.
// 128x128 tile per block, 256 threads = 4 waves in 2x2, each wave 64x64 (4x4 MFMA frags).
// EPI 0: scatter into Q/K/V [B=2][H=16][S=2048][64] fp16  (N=3072)
// EPI 1: out fp32 [M][1024] += bias                       (N=1024)
template<int EPI>
__global__ __launch_bounds__(256) void gemm_k(
    const f16* __restrict__ A, const f16* __restrict__ B, int K,
    f16* __restrict__ qb, f16* __restrict__ kb, f16* __restrict__ vb,
    float* __restrict__ outF, const float* __restrict__ bias)
{
    __shared__ f16 as[128][40];   // pad 32+8 -> 80B rows, 16B aligned, ~2-way banks
    __shared__ f16 bs[128][40];
    const int t = threadIdx.x;
    const int m0 = blockIdx.y * 128, n0 = blockIdx.x * 128;
    const int lane = t & 63, wv = t >> 6;
    const int wm = wv >> 1, wn = wv & 1;
    const int lr = lane & 15, g = lane >> 4;
    f32x4 acc[4][4] = {};

    for (int k0 = 0; k0 < K; k0 += 32) {
        __syncthreads();
        #pragma unroll
        for (int it = 0; it < 2; ++it) {
            int c = t + it * 256;          // 512 chunks of 16B: 128 rows x 4
            int row = c >> 2, cp = c & 3;
            *reinterpret_cast<int4*>(&as[row][cp * 8]) =
                *reinterpret_cast<const int4*>(&A[(size_t)(m0 + row) * K + k0 + cp * 8]);
            *reinterpret_cast<int4*>(&bs[row][cp * 8]) =
                *reinterpret_cast<const int4*>(&B[(size_t)(n0 + row) * K + k0 + cp * 8]);
        }
        __syncthreads();
        f16x8 af[4], bf[4];
        #pragma unroll
        for (int mt = 0; mt < 4; ++mt)
            af[mt] = *reinterpret_cast<const f16x8*>(&as[wm * 64 + mt * 16 + lr][g * 8]);
        #pragma unroll
        for (int nt = 0; nt < 4; ++nt)
            bf[nt] = *reinterpret_cast<const f16x8*>(&bs[wn * 64 + nt * 16 + lr][g * 8]);
        #pragma unroll
        for (int mt = 0; mt < 4; ++mt)
            #pragma unroll
            for (int nt = 0; nt < 4; ++nt)
                acc[mt][nt] = MFMA16(af[mt], bf[nt], acc[mt][nt]);
    }

    // C/D layout: col = lane&15 (n), row = 4*(lane>>4)+i (m)   [guide §3, m89]
    #pragma unroll
    for (int mt = 0; mt < 4; ++mt) {
        #pragma unroll
        for (int nt = 0; nt < 4; ++nt) {
            #pragma unroll
            for (int i = 0; i < 4; ++i) {
                int m = m0 + wm * 64 + mt * 16 + 4 * g + i;
                int n = n0 + wn * 64 + nt * 16 + lr;
                float val = acc[mt][nt][i];
                if (EPI == 0) {
                    int which = n >> 10, h = (n >> 6) & 15, d = n & 63;
                    int b = m >> 11, s = m & 2047;
                    f16* dst = (which == 0) ? qb : (which == 1) ? kb : vb;
                    dst[((size_t)((b << 4) + h) * 2048 + s) * 64 + d] = (f16)val;
                } else {
                    outF[(size_t)m * 1024 + n] = val + bias[n];
                }
            }
        }
    }
}

// ---------------------------------------------------------------- flash attention
// grid = B*H*(S/128) = 512 blocks, 256 threads = 4 waves, wave w owns 32 q-rows.
// Swapped formulation: S^T = K @ Q^T (so C-layout col = q -> per-lane softmax state),
// O^T = V^T @ P^T. KV tile = 64. Reference scale is *8 (divide by head_dim^-0.5).
__global__ __launch_bounds__(256) void attn_k(
    const f16* __restrict__ Q, const f16* __restrict__ K, const f16* __restrict__ V,
    f16* __restrict__ ctx)
{
    __shared__ f16 lk[64][72];        // K tile [kk][d], pad->144B rows
    __shared__ f16 lvt[64][72];       // V^T tile [d][kk]
    __shared__ f16 lp[4][32][72];     // per-wave P [q_local][kk]
    const int t = threadIdx.x, w = t >> 6, lane = t & 63;
    const int lr = lane & 15, g = lane >> 4;
    const int bid = blockIdx.x;
    const int qblk = bid & 15;        // S/128 = 16
    const int h = (bid >> 4) & 15;
    const int b = bid >> 8;
    const int q0 = qblk * 128;
    const size_t base = ((size_t)(b * 16 + h)) * 2048 * 64;
    const f16* Qb = Q + base;
    const f16* Kb = K + base;
    const f16* Vb = V + base;
    const int qw0 = q0 + w * 32;

    // Q fragments held in registers across the kv loop (B-frag: n=q=lr, k=d=8g+j)
    f16x8 qf[2][2];
    #pragma unroll
    for (int nt = 0; nt < 2; ++nt) {
        int qrow = qw0 + nt * 16 + lr;
        #pragma unroll
        for (int ks = 0; ks < 2; ++ks)
            qf[nt][ks] = *reinterpret_cast<const f16x8*>(&Qb[(size_t)qrow * 64 + ks * 32 + g * 8]);
    }

    f32x4 o[4][2] = {};               // O^T: m-tiles = d (4), n-tiles = q (2)
    float mrun[2] = { -1e30f, -1e30f };
    float lrun[2] = { 0.f, 0.f };
    const int nkv = (q0 + 128) >> 6;

    for (int kbI = 0; kbI < nkv; ++kbI) {
        const int kv0 = kbI << 6;
        __syncthreads();
        #pragma unroll
        for (int it = 0; it < 2; ++it) {
            int c = t + it * 256;
            {   // K tile: linear, 16B chunks (64 rows x 8 chunks)
                int row = c >> 3, cp = c & 7;
                *reinterpret_cast<int4*>(&lk[row][cp * 8]) =
                    *reinterpret_cast<const int4*>(&Kb[(size_t)(kv0 + row) * 64 + cp * 8]);
            }
            {   // V^T tile: transpose during store; per-wave lanes span rows -> ~2-way banks
                int row = c & 63, d0 = (c >> 6) * 8;
                f16x8 vv = *reinterpret_cast<const f16x8*>(&Vb[(size_t)(kv0 + row) * 64 + d0]);
                #pragma unroll
                for (int jj = 0; jj < 8; ++jj) lvt[d0 + jj][row] = vv[jj];
            }
        }
        __syncthreads();

        if (kv0 <= qw0 + 31) {        // causally relevant for this wave's rows
            // S^T = K @ Q^T : A-frag = K[kk][d], B-frag = Q
            f32x4 st[4][2] = {};
            #pragma unroll
            for (int mt = 0; mt < 4; ++mt) {
                f16x8 ak[2];
                #pragma unroll
                for (int ks = 0; ks < 2; ++ks)
                    ak[ks] = *reinterpret_cast<const f16x8*>(&lk[mt * 16 + lr][ks * 32 + g * 8]);
                #pragma unroll
                for (int nt = 0; nt < 2; ++nt)
                    #pragma unroll
                    for (int ks = 0; ks < 2; ++ks)
                        st[mt][nt] = MFMA16(ak[ks], qf[nt][ks], st[mt][nt]);
            }
            // mask + scale + online softmax (per q = per lane-column)
            #pragma unroll
            for (int nt = 0; nt < 2; ++nt) {
                const int qrow = qw0 + nt * 16 + lr;
                float mloc = -1e30f;
                #pragma unroll
                for (int mt = 0; mt < 4; ++mt)
                    #pragma unroll
                    for (int i = 0; i < 4; ++i) {
                        int kkk = kv0 + mt * 16 + 4 * g + i;
                        float sv = st[mt][nt][i] * 8.0f;
                        sv = (kkk <= qrow) ? sv : -1e30f;
                        st[mt][nt][i] = sv;
                        mloc = fmaxf(mloc, sv);
                    }
                mloc = fmaxf(mloc, __shfl_xor(mloc, 16));
                mloc = fmaxf(mloc, __shfl_xor(mloc, 32));
                float mnew = fmaxf(mrun[nt], mloc);
                float sc = exp2f((mrun[nt] - mnew) * LOG2E);
                float ls = 0.f;
                #pragma unroll
                for (int mt = 0; mt < 4; ++mt) {
                    f16x4 pk;
                    #pragma unroll
                    for (int i = 0; i < 4; ++i) {
                        float p = exp2f((st[mt][nt][i] - mnew) * LOG2E);
                        ls += p;
                        pk[i] = (f16)p;
                    }
                    // P[q][kk]: 4 contiguous kk per store (8B)
                    *reinterpret_cast<f16x4*>(&lp[w][nt * 16 + lr][mt * 16 + 4 * g]) = pk;
                }
                ls += __shfl_xor(ls, 16);
                ls += __shfl_xor(ls, 32);
                lrun[nt] = lrun[nt] * sc + ls;
                mrun[nt] = mnew;
                #pragma unroll
                for (int mo = 0; mo < 4; ++mo)
                    #pragma unroll
                    for (int i = 0; i < 4; ++i)
                        o[mo][nt][i] *= sc;
            }
            // O^T += V^T @ P^T : A-frag = V^T[d][kk], B-frag = P^T (n=q=lr, k=kk)
            f16x8 pf[2][2];
            #pragma unroll
            for (int nt = 0; nt < 2; ++nt)
                #pragma unroll
                for (int ks = 0; ks < 2; ++ks)
                    pf[nt][ks] = *reinterpret_cast<const f16x8*>(&lp[w][nt * 16 + lr][ks * 32 + g * 8]);
            #pragma unroll
            for (int mo = 0; mo < 4; ++mo) {
                f16x8 av[2];
                #pragma unroll
                for (int ks = 0; ks < 2; ++ks)
                    av[ks] = *reinterpret_cast<const f16x8*>(&lvt[mo * 16 + lr][ks * 32 + g * 8]);
                #pragma unroll
                for (int nt = 0; nt < 2; ++nt)
                    #pragma unroll
                    for (int ks = 0; ks < 2; ++ks)
                        o[mo][nt] = MFMA16(av[ks], pf[nt][ks], o[mo][nt]);
            }
        }
    }

    // epilogue: ctx[b*2048+q][h*64+d] fp16
    #pragma unroll
    for (int nt = 0; nt < 2; ++nt) {
        float inv = 1.0f / lrun[nt];
        int qrow = qw0 + nt * 16 + lr;
        size_t rowoff = ((size_t)(b * 2048 + qrow)) * 1024 + h * 64;
        #pragma unroll
        for (int mo = 0; mo < 4; ++mo) {
            f16x4 ov;
            #pragma unroll
            for (int i = 0; i < 4; ++i) ov[i] = (f16)(o[mo][nt][i] * inv);
            *reinterpret_cast<f16x4*>(&ctx[rowoff + mo * 16 + 4 * g]) = ov;
        }
    }
}

// ---------------------------------------------------------------- launch
extern "C" void kernel_launch(void* const* d_in, const int* in_sizes, int n_in,
                              void* d_out, int out_size, void* d_ws, size_t ws_size,
                              hipStream_t stream) {
    const float* x      = (const float*)d_in[0];   // [2,2048,1024]
    const float* w_qkv  = (const float*)d_in[1];   // [3072,1024]
    const float* w_proj = (const float*)d_in[2];   // [1024,1024]
    const float* b_proj = (const float*)d_in[3];   // [1024]
    float* out = (float*)d_out;                    // [2,2048,1024] fp32

    char* p = (char*)d_ws;
    f16* xh     = (f16*)p; p += (size_t)4096 * 1024 * 2;        // 8 MB
    f16* wqkvh  = (f16*)p; p += (size_t)3072 * 1024 * 2;        // 6 MB
    f16* wprojh = (f16*)p; p += (size_t)1024 * 1024 * 2;        // 2 MB
    f16* qbuf   = (f16*)p; p += (size_t)2 * 16 * 2048 * 64 * 2; // 8 MB
    f16* kbuf   = (f16*)p; p += (size_t)2 * 16 * 2048 * 64 * 2; // 8 MB
    f16* vbuf   = (f16*)p; p += (size_t)2 * 16 * 2048 * 64 * 2; // 8 MB
    f16* ctx    = (f16*)p; p += (size_t)4096 * 1024 * 2;        // 8 MB  (total 48 MB)

    cvt_f32_f16<<<4096, 256, 0, stream>>>(x, xh, 1048576);
    cvt_f32_f16<<<3072, 256, 0, stream>>>(w_qkv, wqkvh, 786432);
    cvt_f32_f16<<<1024, 256, 0, stream>>>(w_proj, wprojh, 262144);

    // qkv = x @ w_qkv^T, scattered into Q/K/V [B,H,S,64]
    gemm_k<0><<<dim3(24, 32), 256, 0, stream>>>(xh, wqkvh, 1024, qbuf, kbuf, vbuf, nullptr, nullptr);

    attn_k<<<512, 256, 0, stream>>>(qbuf, kbuf, vbuf, ctx);

    // out = ctx @ w_proj^T + b_proj
    gemm_k<1><<<dim3(8, 32), 256, 0, stream>>>(ctx, wprojh, 1024, nullptr, nullptr, nullptr, out, b_proj);
}

// Round 3
// 224.189 us; speedup vs baseline: 1.1415x; 1.1415x over previous
//
#include <hip/hip_runtime.h>

typedef _Float16 f16;
typedef _Float16 f16x4 __attribute__((ext_vector_type(4)));
typedef _Float16 f16x8 __attribute__((ext_vector_type(8)));
typedef float f32x4 __attribute__((ext_vector_type(4)));

#define MFMA16(a, b, c) __builtin_amdgcn_mfma_f32_16x16x32_f16(a, b, c, 0, 0, 0)
#define QSCALE 11.5415603f   /* 8 * log2(e): folds the reference's x8 scale + exp2 domain */

typedef const __attribute__((address_space(1))) void* gp1_t;
typedef __attribute__((address_space(3))) void* lp3_t;
__device__ __forceinline__ void gld16(const void* g, void* l) {
    __builtin_amdgcn_global_load_lds((gp1_t)g, (lp3_t)l, 16, 0, 0);
}

// ---------------------------------------------------------------- fused fp32->fp16 converts
__global__ __launch_bounds__(256) void cvt_all(
    const float* __restrict__ x, const float* __restrict__ wq, const float* __restrict__ wp,
    f16* __restrict__ xh, f16* __restrict__ wqh, f16* __restrict__ wph)
{
    int i = blockIdx.x * 256 + threadIdx.x;          // float4 index, total 2097152 exact
    const float4* src; f16x4* dst; int off;
    if (i < 1048576)      { src = (const float4*)x;  dst = (f16x4*)xh;  off = i; }
    else if (i < 1835008) { src = (const float4*)wq; dst = (f16x4*)wqh; off = i - 1048576; }
    else                  { src = (const float4*)wp; dst = (f16x4*)wph; off = i - 1835008; }
    float4 v = src[off];
    f16x4 o = { (f16)v.x, (f16)v.y, (f16)v.z, (f16)v.w };
    dst[off] = o;
}

// ---------------------------------------------------------------- GEMM C = A @ B^T (m97 structure)
// A [M][K], B [N][K] f16 row-major. 128x128 tile, 4 waves 2x2, 4x4 frags/wave, BK=32,
// linear LDS [128][32] + global_load_lds width-16 staging.
// EPI 0: scatter Q(*QSCALE)/K into [B,H,S,64], V transposed into [B,H,64,S]
// EPI 1: out fp32 [M][1024] + bias
template<int EPI>
__global__ __launch_bounds__(256) void gemm_k(
    const f16* __restrict__ A, const f16* __restrict__ B, int K,
    f16* __restrict__ qb, f16* __restrict__ kb, f16* __restrict__ vt,
    float* __restrict__ outF, const float* __restrict__ bias)
{
    __shared__ f16 as[128 * 32];
    __shared__ f16 bs[128 * 32];
    const int t = threadIdx.x;
    const int m0 = blockIdx.y * 128, n0 = blockIdx.x * 128;
    const int lane = t & 63, wv = t >> 6;
    const int wm = wv >> 1, wn = wv & 1;
    const int lr = lane & 15, g = lane >> 4;
    const int srow = lane >> 2, schk = (lane & 3) * 8;   // 16 rows x 4 chunks of 16B per instr
    const f16* Ab = A + (size_t)m0 * K;
    const f16* Bb = B + (size_t)n0 * K;
    f32x4 acc[4][4] = {};

    for (int k0 = 0; k0 < K; k0 += 32) {
        __syncthreads();                       // previous tile's reads done
        #pragma unroll
        for (int i2 = 0; i2 < 2; ++i2) {
            const int r0 = wv * 32 + i2 * 16;  // wave-uniform
            gld16(&Ab[(size_t)(r0 + srow) * K + k0 + schk], &as[r0 * 32]);
            gld16(&Bb[(size_t)(r0 + srow) * K + k0 + schk], &bs[r0 * 32]);
        }
        __syncthreads();                       // compiler drains vmcnt before barrier
        f16x8 af[4], bf[4];
        #pragma unroll
        for (int mt = 0; mt < 4; ++mt)
            af[mt] = *reinterpret_cast<const f16x8*>(&as[(wm * 64 + mt * 16 + lr) * 32 + g * 8]);
        #pragma unroll
        for (int nt = 0; nt < 4; ++nt)
            bf[nt] = *reinterpret_cast<const f16x8*>(&bs[(wn * 64 + nt * 16 + lr) * 32 + g * 8]);
        #pragma unroll
        for (int mt = 0; mt < 4; ++mt)
            #pragma unroll
            for (int nt = 0; nt < 4; ++nt)
                acc[mt][nt] = MFMA16(af[mt], bf[nt], acc[mt][nt]);
    }

    // C/D layout: col = lane&15 (n), row = 4*(lane>>4)+i (m)
    #pragma unroll
    for (int mt = 0; mt < 4; ++mt) {
        #pragma unroll
        for (int nt = 0; nt < 4; ++nt) {
            const int n = n0 + wn * 64 + nt * 16 + lr;
            const int s0 = m0 + wm * 64 + mt * 16 + 4 * g;   // 4 consecutive m via i
            if (EPI == 0) {
                const int which = n >> 10, h = (n >> 6) & 15, d = n & 63;
                const int b = s0 >> 11, s = s0 & 2047;       // tile never crosses b
                if (which == 2) {
                    f16x4 vv;
                    #pragma unroll
                    for (int i = 0; i < 4; ++i) vv[i] = (f16)acc[mt][nt][i];
                    *reinterpret_cast<f16x4*>(&vt[((size_t)((b << 4) + h) * 64 + d) * 2048 + s]) = vv;
                } else {
                    f16* dst = which ? kb : qb;
                    const float sc = which ? 1.0f : QSCALE;
                    #pragma unroll
                    for (int i = 0; i < 4; ++i)
                        dst[((size_t)((b << 4) + h) * 2048 + (s + i)) * 64 + d] = (f16)(acc[mt][nt][i] * sc);
                }
            } else {
                #pragma unroll
                for (int i = 0; i < 4; ++i)
                    outF[(size_t)(s0 + i) * 1024 + n] = acc[mt][nt][i] + bias[n];
            }
        }
    }
}

// ---------------------------------------------------------------- flash attention v2
// 1 wave per block, 2048 blocks (= 64 q-units x 32 bh). No barriers, no K/V LDS staging
// (L2-served; bh = bid&31 clusters each bh onto one XCD). Blocks launched in descending
// cost order. Swapped QK^T (S^T = K@Q^T) so softmax state is per-lane. KVB = 64.
// Q is pre-scaled by 8*log2(e) -> scores are already in exp2 domain.
__global__ __launch_bounds__(64) void attn_k(
    const f16* __restrict__ Q, const f16* __restrict__ K, const f16* __restrict__ VT,
    f16* __restrict__ ctx)
{
    __shared__ f16 lp[32][72];    // per-wave P tile [q][kk], 144B rows: 8-group bank spread
    const int lane = threadIdx.x;
    const int lr = lane & 15, g = lane >> 4;
    const int bid = blockIdx.x;
    const int j = 63 - (bid >> 5);         // q-unit, descending cost
    const int bh = bid & 31;
    const int b = bh >> 4, h = bh & 15;
    const size_t base = (size_t)bh * (2048 * 64);
    const f16* Qb = Q + base;
    const f16* Kb = K + base;
    const f16* Vb = VT + base;             // [64][2048]
    const int q0 = j << 5;

    f16x8 qf[2][2];
    #pragma unroll
    for (int nt = 0; nt < 2; ++nt)
        #pragma unroll
        for (int ks = 0; ks < 2; ++ks)
            qf[nt][ks] = *reinterpret_cast<const f16x8*>(&Qb[(size_t)(q0 + nt * 16 + lr) * 64 + ks * 32 + g * 8]);

    f32x4 o[4][2] = {};
    float mrun[2] = { -1e30f, -1e30f };
    float lrun[2] = { 0.f, 0.f };
    const int ntiles = (j >> 1) + 1;

#define ATTN_TILE(KV0, MTMAX, MASKED) do {                                              \
    const int kv0_ = (KV0);                                                             \
    f32x4 st[MTMAX][2] = {};                                                            \
    _Pragma("unroll")                                                                   \
    for (int mt = 0; mt < MTMAX; ++mt) {                                                \
        f16x8 ak[2];                                                                    \
        _Pragma("unroll")                                                               \
        for (int ks = 0; ks < 2; ++ks)                                                  \
            ak[ks] = *reinterpret_cast<const f16x8*>(                                   \
                &Kb[(size_t)(kv0_ + mt * 16 + lr) * 64 + ks * 32 + g * 8]);             \
        _Pragma("unroll")                                                               \
        for (int nt = 0; nt < 2; ++nt)                                                  \
            _Pragma("unroll")                                                           \
            for (int ks = 0; ks < 2; ++ks)                                              \
                st[mt][nt] = MFMA16(ak[ks], qf[nt][ks], st[mt][nt]);                    \
    }                                                                                   \
    _Pragma("unroll")                                                                   \
    for (int nt = 0; nt < 2; ++nt) {                                                    \
        const int qrow_ = q0 + nt * 16 + lr;                                            \
        float mloc = -1e30f;                                                            \
        _Pragma("unroll")                                                               \
        for (int mt = 0; mt < MTMAX; ++mt)                                              \
            _Pragma("unroll")                                                           \
            for (int i = 0; i < 4; ++i) {                                               \
                float sv = st[mt][nt][i];                                               \
                if (MASKED) {                                                           \
                    int kkk = kv0_ + mt * 16 + 4 * g + i;                               \
                    sv = (kkk <= qrow_) ? sv : -1e30f;                                  \
                    st[mt][nt][i] = sv;                                                 \
                }                                                                       \
                mloc = fmaxf(mloc, sv);                                                 \
            }                                                                           \
        mloc = fmaxf(mloc, __shfl_xor(mloc, 16));                                       \
        mloc = fmaxf(mloc, __shfl_xor(mloc, 32));                                       \
        if (__any(mloc > mrun[nt] + 8.0f)) {       /* defer-max: skip small growth */   \
            float mnew = fmaxf(mrun[nt], mloc);                                         \
            float sc = exp2f(mrun[nt] - mnew);                                          \
            lrun[nt] *= sc;                                                             \
            _Pragma("unroll")                                                           \
            for (int mo = 0; mo < 4; ++mo)                                              \
                _Pragma("unroll")                                                       \
                for (int i = 0; i < 4; ++i) o[mo][nt][i] *= sc;                         \
            mrun[nt] = mnew;                                                            \
        }                                                                               \
        float ls = 0.f;                                                                 \
        _Pragma("unroll")                                                               \
        for (int mt = 0; mt < MTMAX; ++mt) {                                            \
            f16x4 pk;                                                                   \
            _Pragma("unroll")                                                           \
            for (int i = 0; i < 4; ++i) {                                               \
                float p = exp2f(st[mt][nt][i] - mrun[nt]);                              \
                ls += p; pk[i] = (f16)p;                                                \
            }                                                                           \
            *reinterpret_cast<f16x4*>(&lp[nt * 16 + lr][mt * 16 + 4 * g]) = pk;         \
        }                                                                               \
        ls += __shfl_xor(ls, 16);                                                       \
        ls += __shfl_xor(ls, 32);                                                       \
        lrun[nt] += ls;                                                                 \
    }                                                                                   \
    {                                                                                   \
        constexpr int PVKS = (MTMAX) / 2;                                               \
        f16x8 pf[2][PVKS];                                                              \
        _Pragma("unroll")                                                               \
        for (int nt = 0; nt < 2; ++nt)                                                  \
            _Pragma("unroll")                                                           \
            for (int ks = 0; ks < PVKS; ++ks)                                           \
                pf[nt][ks] = *reinterpret_cast<const f16x8*>(                           \
                    &lp[nt * 16 + lr][ks * 32 + g * 8]);                                \
        _Pragma("unroll")                                                               \
        for (int mo = 0; mo < 4; ++mo) {                                                \
            f16x8 av[PVKS];                                                             \
            _Pragma("unroll")                                                           \
            for (int ks = 0; ks < PVKS; ++ks)                                           \
                av[ks] = *reinterpret_cast<const f16x8*>(                               \
                    &Vb[(size_t)(mo * 16 + lr) * 2048 + kv0_ + ks * 32 + g * 8]);       \
            _Pragma("unroll")                                                           \
            for (int nt = 0; nt < 2; ++nt)                                              \
                _Pragma("unroll")                                                       \
                for (int ks = 0; ks < PVKS; ++ks)                                       \
                    o[mo][nt] = MFMA16(av[ks], pf[nt][ks], o[mo][nt]);                  \
        }                                                                               \
    }                                                                                   \
} while (0)

    for (int tt = 0; tt < ntiles - 1; ++tt)
        ATTN_TILE(tt << 6, 4, false);              // full tiles: no mask
    {
        const int kvl = (ntiles - 1) << 6;         // diagonal tile: masked
        if (j & 1) ATTN_TILE(kvl, 4, true);
        else       ATTN_TILE(kvl, 2, true);        // upper half fully masked -> skipped
    }
#undef ATTN_TILE

    // epilogue: ctx[b*2048+q][h*64+d] f16
    #pragma unroll
    for (int nt = 0; nt < 2; ++nt) {
        const float inv = 1.0f / lrun[nt];
        const int qrow = q0 + nt * 16 + lr;
        const size_t rowoff = ((size_t)(b * 2048 + qrow)) * 1024 + h * 64;
        #pragma unroll
        for (int mo = 0; mo < 4; ++mo) {
            f16x4 ov;
            #pragma unroll
            for (int i = 0; i < 4; ++i) ov[i] = (f16)(o[mo][nt][i] * inv);
            *reinterpret_cast<f16x4*>(&ctx[rowoff + mo * 16 + 4 * g]) = ov;
        }
    }
}

// ---------------------------------------------------------------- launch
extern "C" void kernel_launch(void* const* d_in, const int* in_sizes, int n_in,
                              void* d_out, int out_size, void* d_ws, size_t ws_size,
                              hipStream_t stream) {
    const float* x      = (const float*)d_in[0];   // [2,2048,1024]
    const float* w_qkv  = (const float*)d_in[1];   // [3072,1024]
    const float* w_proj = (const float*)d_in[2];   // [1024,1024]
    const float* b_proj = (const float*)d_in[3];   // [1024]
    float* out = (float*)d_out;                    // [2,2048,1024] fp32

    char* p = (char*)d_ws;
    f16* xh     = (f16*)p; p += (size_t)4096 * 1024 * 2;        // 8 MB
    f16* wqkvh  = (f16*)p; p += (size_t)3072 * 1024 * 2;        // 6 MB
    f16* wprojh = (f16*)p; p += (size_t)1024 * 1024 * 2;        // 2 MB
    f16* qbuf   = (f16*)p; p += (size_t)2 * 16 * 2048 * 64 * 2; // 8 MB  [B,H,S,64], pre-scaled
    f16* kbuf   = (f16*)p; p += (size_t)2 * 16 * 2048 * 64 * 2; // 8 MB  [B,H,S,64]
    f16* vtbuf  = (f16*)p; p += (size_t)2 * 16 * 64 * 2048 * 2; // 8 MB  [B,H,64,S] transposed
    f16* ctx    = (f16*)p; p += (size_t)4096 * 1024 * 2;        // 8 MB  (total 48 MB)

    cvt_all<<<8192, 256, 0, stream>>>(x, w_qkv, w_proj, xh, wqkvh, wprojh);

    gemm_k<0><<<dim3(24, 32), 256, 0, stream>>>(xh, wqkvh, 1024, qbuf, kbuf, vtbuf, nullptr, nullptr);

    attn_k<<<2048, 64, 0, stream>>>(qbuf, kbuf, vtbuf, ctx);

    gemm_k<1><<<dim3(8, 32), 256, 0, stream>>>(ctx, wprojh, 1024, nullptr, nullptr, nullptr, out, b_proj);
}

// Round 4
// 223.500 us; speedup vs baseline: 1.1450x; 1.0031x over previous
//
#include <hip/hip_runtime.h>

typedef _Float16 f16;
typedef _Float16 f16x4 __attribute__((ext_vector_type(4)));
typedef _Float16 f16x8 __attribute__((ext_vector_type(8)));
typedef float f32x4 __attribute__((ext_vector_type(4)));

#define MFMA16(a, b, c) __builtin_amdgcn_mfma_f32_16x16x32_f16(a, b, c, 0, 0, 0)
#define QSCALE 11.5415603f   /* 8 * log2(e): folds the reference's x8 scale + exp2 domain */

typedef const __attribute__((address_space(1))) void* gp1_t;
typedef __attribute__((address_space(3))) void* lp3_t;
__device__ __forceinline__ void gld16(const void* g, void* l) {
    __builtin_amdgcn_global_load_lds((gp1_t)g, (lp3_t)l, 16, 0, 0);
}

// ---------------------------------------------------------------- fused fp32->fp16 converts
__global__ __launch_bounds__(256) void cvt_all(
    const float* __restrict__ x, const float* __restrict__ wq, const float* __restrict__ wp,
    f16* __restrict__ xh, f16* __restrict__ wqh, f16* __restrict__ wph)
{
    int i = blockIdx.x * 256 + threadIdx.x;          // float4 index, total 2097152 exact
    const float4* src; f16x4* dst; int off;
    if (i < 1048576)      { src = (const float4*)x;  dst = (f16x4*)xh;  off = i; }
    else if (i < 1835008) { src = (const float4*)wq; dst = (f16x4*)wqh; off = i - 1048576; }
    else                  { src = (const float4*)wp; dst = (f16x4*)wph; off = i - 1835008; }
    float4 v = src[off];
    f16x4 o = { (f16)v.x, (f16)v.y, (f16)v.z, (f16)v.w };
    dst[off] = o;
}

// ---------------------------------------------------------------- GEMM C = A @ B^T (m97 structure)
// (unchanged this round — gemm counters needed before editing)
template<int EPI>
__global__ __launch_bounds__(256) void gemm_k(
    const f16* __restrict__ A, const f16* __restrict__ B, int K,
    f16* __restrict__ qb, f16* __restrict__ kb, f16* __restrict__ vt,
    float* __restrict__ outF, const float* __restrict__ bias)
{
    __shared__ f16 as[128 * 32];
    __shared__ f16 bs[128 * 32];
    const int t = threadIdx.x;
    const int m0 = blockIdx.y * 128, n0 = blockIdx.x * 128;
    const int lane = t & 63, wv = t >> 6;
    const int wm = wv >> 1, wn = wv & 1;
    const int lr = lane & 15, g = lane >> 4;
    const int srow = lane >> 2, schk = (lane & 3) * 8;
    const f16* Ab = A + (size_t)m0 * K;
    const f16* Bb = B + (size_t)n0 * K;
    f32x4 acc[4][4] = {};

    for (int k0 = 0; k0 < K; k0 += 32) {
        __syncthreads();
        #pragma unroll
        for (int i2 = 0; i2 < 2; ++i2) {
            const int r0 = wv * 32 + i2 * 16;  // wave-uniform
            gld16(&Ab[(size_t)(r0 + srow) * K + k0 + schk], &as[r0 * 32]);
            gld16(&Bb[(size_t)(r0 + srow) * K + k0 + schk], &bs[r0 * 32]);
        }
        __syncthreads();
        f16x8 af[4], bf[4];
        #pragma unroll
        for (int mt = 0; mt < 4; ++mt)
            af[mt] = *reinterpret_cast<const f16x8*>(&as[(wm * 64 + mt * 16 + lr) * 32 + g * 8]);
        #pragma unroll
        for (int nt = 0; nt < 4; ++nt)
            bf[nt] = *reinterpret_cast<const f16x8*>(&bs[(wn * 64 + nt * 16 + lr) * 32 + g * 8]);
        #pragma unroll
        for (int mt = 0; mt < 4; ++mt)
            #pragma unroll
            for (int nt = 0; nt < 4; ++nt)
                acc[mt][nt] = MFMA16(af[mt], bf[nt], acc[mt][nt]);
    }

    #pragma unroll
    for (int mt = 0; mt < 4; ++mt) {
        #pragma unroll
        for (int nt = 0; nt < 4; ++nt) {
            const int n = n0 + wn * 64 + nt * 16 + lr;
            const int s0 = m0 + wm * 64 + mt * 16 + 4 * g;
            if (EPI == 0) {
                const int which = n >> 10, h = (n >> 6) & 15, d = n & 63;
                const int b = s0 >> 11, s = s0 & 2047;
                if (which == 2) {
                    f16x4 vv;
                    #pragma unroll
                    for (int i = 0; i < 4; ++i) vv[i] = (f16)acc[mt][nt][i];
                    *reinterpret_cast<f16x4*>(&vt[((size_t)((b << 4) + h) * 64 + d) * 2048 + s]) = vv;
                } else {
                    f16* dst = which ? kb : qb;
                    const float sc = which ? 1.0f : QSCALE;
                    #pragma unroll
                    for (int i = 0; i < 4; ++i)
                        dst[((size_t)((b << 4) + h) * 2048 + (s + i)) * 64 + d] = (f16)(acc[mt][nt][i] * sc);
                }
            } else {
                #pragma unroll
                for (int i = 0; i < 4; ++i)
                    outF[(size_t)(s0 + i) * 1024 + n] = acc[mt][nt][i] + bias[n];
            }
        }
    }
}

// ---------------------------------------------------------------- flash attention v3
// KV-split flash-decoding: units j>=32 (long half) are split into two kv-range waves
// (s=0: tiles [0,H), s=1: [H, ntt)); each writes partial (m, l, O/l as f16).
// Units j<32 write ctx directly. Grid 3072 one-wave blocks = 12 waves/CU.
// Per-lane partial l-sum deferred to the epilogue (saves 4 shuffles/tile).
__global__ __launch_bounds__(64) void attn_k(
    const f16* __restrict__ Q, const f16* __restrict__ K, const f16* __restrict__ VT,
    f16* __restrict__ ctx, f16* __restrict__ opart,
    float* __restrict__ mpart, float* __restrict__ lpart)
{
    __shared__ f16 lp[32][72];
    const int lane = threadIdx.x;
    const int lr = lane & 15, g = lane >> 4;
    const int bid = blockIdx.x;
    int j, s; bool split;
    if (bid < 2048) { split = true;  j = 63 - (bid >> 6); s = (bid >> 5) & 1; }
    else            { split = false; j = 31 - ((bid - 2048) >> 5); s = 0; }
    const int bh = bid & 31;
    const int b = bh >> 4, h = bh & 15;
    const size_t base = (size_t)bh * (2048 * 64);
    const f16* Qb = Q + base;
    const f16* Kb = K + base;
    const f16* Vb = VT + base;             // [64][2048]
    const int q0 = j << 5;
    const int ntt = (j >> 1) + 1;          // total kv tiles for this unit
    const int H = (ntt + 1) >> 1;
    const int t0 = split ? (s ? H : 0) : 0;
    const int t1 = split ? (s ? ntt : H) : ntt;
    const bool diag = (t1 == ntt);         // this wave owns the masked diagonal tile

    f16x8 qf[2][2];
    #pragma unroll
    for (int nt = 0; nt < 2; ++nt)
        #pragma unroll
        for (int ks = 0; ks < 2; ++ks)
            qf[nt][ks] = *reinterpret_cast<const f16x8*>(&Qb[(size_t)(q0 + nt * 16 + lr) * 64 + ks * 32 + g * 8]);

    f32x4 o[4][2] = {};
    float mrun[2] = { -1e30f, -1e30f };
    float lsum[2] = { 0.f, 0.f };          // per-lane partial; reduced once in epilogue

#define ATTN_TILE(KV0, MTMAX, MASKED) do {                                              \
    const int kv0_ = (KV0);                                                             \
    f32x4 st[MTMAX][2] = {};                                                            \
    _Pragma("unroll")                                                                   \
    for (int mt = 0; mt < MTMAX; ++mt) {                                                \
        f16x8 ak[2];                                                                    \
        _Pragma("unroll")                                                               \
        for (int ks = 0; ks < 2; ++ks)                                                  \
            ak[ks] = *reinterpret_cast<const f16x8*>(                                   \
                &Kb[(size_t)(kv0_ + mt * 16 + lr) * 64 + ks * 32 + g * 8]);             \
        _Pragma("unroll")                                                               \
        for (int nt = 0; nt < 2; ++nt)                                                  \
            _Pragma("unroll")                                                           \
            for (int ks = 0; ks < 2; ++ks)                                              \
                st[mt][nt] = MFMA16(ak[ks], qf[nt][ks], st[mt][nt]);                    \
    }                                                                                   \
    _Pragma("unroll")                                                                   \
    for (int nt = 0; nt < 2; ++nt) {                                                    \
        const int qrow_ = q0 + nt * 16 + lr;                                            \
        float mloc = -1e30f;                                                            \
        _Pragma("unroll")                                                               \
        for (int mt = 0; mt < MTMAX; ++mt)                                              \
            _Pragma("unroll")                                                           \
            for (int i = 0; i < 4; ++i) {                                               \
                float sv = st[mt][nt][i];                                               \
                if (MASKED) {                                                           \
                    int kkk = kv0_ + mt * 16 + 4 * g + i;                               \
                    sv = (kkk <= qrow_) ? sv : -1e30f;                                  \
                    st[mt][nt][i] = sv;                                                 \
                }                                                                       \
                mloc = fmaxf(mloc, sv);                                                 \
            }                                                                           \
        mloc = fmaxf(mloc, __shfl_xor(mloc, 16));                                       \
        mloc = fmaxf(mloc, __shfl_xor(mloc, 32));                                       \
        if (__any(mloc > mrun[nt] + 8.0f)) {       /* defer-max */                      \
            float mnew = fmaxf(mrun[nt], mloc);                                         \
            float sc = exp2f(mrun[nt] - mnew);                                          \
            lsum[nt] *= sc;                                                             \
            _Pragma("unroll")                                                           \
            for (int mo = 0; mo < 4; ++mo)                                              \
                _Pragma("unroll")                                                       \
                for (int i = 0; i < 4; ++i) o[mo][nt][i] *= sc;                         \
            mrun[nt] = mnew;                                                            \
        }                                                                               \
        float ls = 0.f;                                                                 \
        _Pragma("unroll")                                                               \
        for (int mt = 0; mt < MTMAX; ++mt) {                                            \
            f16x4 pk;                                                                   \
            _Pragma("unroll")                                                           \
            for (int i = 0; i < 4; ++i) {                                               \
                float p = exp2f(st[mt][nt][i] - mrun[nt]);                              \
                ls += p; pk[i] = (f16)p;                                                \
            }                                                                           \
            *reinterpret_cast<f16x4*>(&lp[nt * 16 + lr][mt * 16 + 4 * g]) = pk;         \
        }                                                                               \
        lsum[nt] += ls;                                                                 \
    }                                                                                   \
    {                                                                                   \
        constexpr int PVKS = (MTMAX) / 2;                                               \
        f16x8 pf[2][PVKS];                                                              \
        _Pragma("unroll")                                                               \
        for (int nt = 0; nt < 2; ++nt)                                                  \
            _Pragma("unroll")                                                           \
            for (int ks = 0; ks < PVKS; ++ks)                                           \
                pf[nt][ks] = *reinterpret_cast<const f16x8*>(                           \
                    &lp[nt * 16 + lr][ks * 32 + g * 8]);                                \
        _Pragma("unroll")                                                               \
        for (int mo = 0; mo < 4; ++mo) {                                                \
            f16x8 av[PVKS];                                                             \
            _Pragma("unroll")                                                           \
            for (int ks = 0; ks < PVKS; ++ks)                                           \
                av[ks] = *reinterpret_cast<const f16x8*>(                               \
                    &Vb[(size_t)(mo * 16 + lr) * 2048 + kv0_ + ks * 32 + g * 8]);       \
            _Pragma("unroll")                                                           \
            for (int nt = 0; nt < 2; ++nt)                                              \
                _Pragma("unroll")                                                       \
                for (int ks = 0; ks < PVKS; ++ks)                                       \
                    o[mo][nt] = MFMA16(av[ks], pf[nt][ks], o[mo][nt]);                  \
        }                                                                               \
    }                                                                                   \
} while (0)

    const int tEnd = t1 - (diag ? 1 : 0);
    for (int tt = t0; tt < tEnd; ++tt)
        ATTN_TILE(tt << 6, 4, false);              // full tiles
    if (diag) {
        const int kvl = (ntt - 1) << 6;            // diagonal tile: masked
        if (j & 1) ATTN_TILE(kvl, 4, true);
        else       ATTN_TILE(kvl, 2, true);        // upper half fully masked
    }
#undef ATTN_TILE

    #pragma unroll
    for (int nt = 0; nt < 2; ++nt) {
        float l = lsum[nt];
        l += __shfl_xor(l, 16);
        l += __shfl_xor(l, 32);
        const float inv = 1.0f / l;
        const int ql = nt * 16 + lr;               // local q (0..31)
        if (!split) {
            const size_t rowoff = ((size_t)(b * 2048 + q0 + ql)) * 1024 + h * 64;
            #pragma unroll
            for (int mo = 0; mo < 4; ++mo) {
                f16x4 ov;
                #pragma unroll
                for (int i = 0; i < 4; ++i) ov[i] = (f16)(o[mo][nt][i] * inv);
                *reinterpret_cast<f16x4*>(&ctx[rowoff + mo * 16 + 4 * g]) = ov;
            }
        } else {
            const int mi = ((s * 32 + bh) * 32 + (j - 32)) * 32 + ql;
            #pragma unroll
            for (int mo = 0; mo < 4; ++mo) {
                f16x4 ov;
                #pragma unroll
                for (int i = 0; i < 4; ++i) ov[i] = (f16)(o[mo][nt][i] * inv);
                *reinterpret_cast<f16x4*>(&opart[(size_t)mi * 64 + mo * 16 + 4 * g]) = ov;
            }
            if (g == 0) { mpart[mi] = mrun[nt]; lpart[mi] = l; }
        }
    }
}

// ---------------------------------------------------------------- combine partials (j>=32 half)
__global__ __launch_bounds__(256) void combine_k(
    const f16* __restrict__ opart, const float* __restrict__ mpart,
    const float* __restrict__ lpart, f16* __restrict__ ctx)
{
    const int blk = blockIdx.x;            // 1024 = bh(32) x jj(32)
    const int bh = blk >> 5, jj = blk & 31;
    const int b = bh >> 4, h = bh & 15;
    const int t = threadIdx.x;
    const int q = t >> 3, dc = (t & 7) * 8;
    const int mi0 = (bh * 32 + jj) * 32 + q;
    const int mi1 = mi0 + 32768;
    const float m0 = mpart[mi0], m1 = mpart[mi1];
    const float l0 = lpart[mi0], l1 = lpart[mi1];
    const float mx = fmaxf(m0, m1);
    const float a0 = l0 * exp2f(m0 - mx);
    const float a1 = l1 * exp2f(m1 - mx);
    const float r = 1.0f / (a0 + a1);
    const float c0 = a0 * r, c1 = a1 * r;
    f16x8 v0 = *reinterpret_cast<const f16x8*>(&opart[(size_t)mi0 * 64 + dc]);
    f16x8 v1 = *reinterpret_cast<const f16x8*>(&opart[(size_t)mi1 * 64 + dc]);
    f16x8 outv;
    #pragma unroll
    for (int i = 0; i < 8; ++i) outv[i] = (f16)(c0 * (float)v0[i] + c1 * (float)v1[i]);
    const int qg = (jj + 32) * 32 + q;     // global q row (>= 1024)
    *reinterpret_cast<f16x8*>(&ctx[((size_t)(b * 2048 + qg)) * 1024 + h * 64 + dc]) = outv;
}

// ---------------------------------------------------------------- launch
extern "C" void kernel_launch(void* const* d_in, const int* in_sizes, int n_in,
                              void* d_out, int out_size, void* d_ws, size_t ws_size,
                              hipStream_t stream) {
    const float* x      = (const float*)d_in[0];   // [2,2048,1024]
    const float* w_qkv  = (const float*)d_in[1];   // [3072,1024]
    const float* w_proj = (const float*)d_in[2];   // [1024,1024]
    const float* b_proj = (const float*)d_in[3];   // [1024]
    float* out = (float*)d_out;                    // [2,2048,1024] fp32

    char* p = (char*)d_ws;
    f16* xh     = (f16*)p; p += (size_t)4096 * 1024 * 2;        // 8 MB (reused as opart)
    f16* wqkvh  = (f16*)p; p += (size_t)3072 * 1024 * 2;        // 6 MB (reused as m/l parts)
    f16* wprojh = (f16*)p; p += (size_t)1024 * 1024 * 2;        // 2 MB
    f16* qbuf   = (f16*)p; p += (size_t)2 * 16 * 2048 * 64 * 2; // 8 MB  [B,H,S,64], pre-scaled
    f16* kbuf   = (f16*)p; p += (size_t)2 * 16 * 2048 * 64 * 2; // 8 MB  [B,H,S,64]
    f16* vtbuf  = (f16*)p; p += (size_t)2 * 16 * 64 * 2048 * 2; // 8 MB  [B,H,64,S] transposed
    f16* ctx    = (f16*)p; p += (size_t)4096 * 1024 * 2;        // 8 MB  (total 48 MB)

    // dead-after-gemm0 buffers recycled for attention partials:
    f16*   opart = xh;                       // 2*32*32*32*64 f16 = 8 MB
    float* mpart = (float*)wqkvh;            // 65536 f32
    float* lpart = mpart + 65536;            // 65536 f32

    cvt_all<<<8192, 256, 0, stream>>>(x, w_qkv, w_proj, xh, wqkvh, wprojh);

    gemm_k<0><<<dim3(24, 32), 256, 0, stream>>>(xh, wqkvh, 1024, qbuf, kbuf, vtbuf, nullptr, nullptr);

    attn_k<<<3072, 64, 0, stream>>>(qbuf, kbuf, vtbuf, ctx, opart, mpart, lpart);

    combine_k<<<1024, 256, 0, stream>>>(opart, mpart, lpart, ctx);

    gemm_k<1><<<dim3(8, 32), 256, 0, stream>>>(ctx, wprojh, 1024, nullptr, nullptr, nullptr, out, b_proj);
}

// Round 5
// 222.159 us; speedup vs baseline: 1.1519x; 1.0060x over previous
//
#include <hip/hip_runtime.h>

typedef _Float16 f16;
typedef _Float16 f16x4 __attribute__((ext_vector_type(4)));
typedef _Float16 f16x8 __attribute__((ext_vector_type(8)));
typedef float f32x4 __attribute__((ext_vector_type(4)));

#define MFMA16(a, b, c) __builtin_amdgcn_mfma_f32_16x16x32_f16(a, b, c, 0, 0, 0)
#define QSCALE 11.5415603f   /* 8 * log2(e): folds the reference's x8 scale + exp2 domain */

typedef const __attribute__((address_space(1))) void* gp1_t;
typedef __attribute__((address_space(3))) void* lp3_t;
__device__ __forceinline__ void gld16(const void* g, void* l) {
    __builtin_amdgcn_global_load_lds((gp1_t)g, (lp3_t)l, 16, 0, 0);
}

// chunk-count / prefix over q-units: nc(j) = 1 (j<22), 2 (j<44), 3 (else); 126 chunks per bh
__device__ __forceinline__ int unit_nc(int j)     { return j < 22 ? 1 : (j < 44 ? 2 : 3); }
__device__ __forceinline__ int unit_prefix(int j) { return j < 22 ? j : (j < 44 ? 22 + 2 * (j - 22) : 66 + 3 * (j - 44)); }

// ---------------------------------------------------------------- fused fp32->fp16 converts
__global__ __launch_bounds__(256) void cvt_all(
    const float* __restrict__ x, const float* __restrict__ wq, const float* __restrict__ wp,
    f16* __restrict__ xh, f16* __restrict__ wqh, f16* __restrict__ wph)
{
    int i = blockIdx.x * 256 + threadIdx.x;          // float4 index, total 2097152 exact
    const float4* src; f16x4* dst; int off;
    if (i < 1048576)      { src = (const float4*)x;  dst = (f16x4*)xh;  off = i; }
    else if (i < 1835008) { src = (const float4*)wq; dst = (f16x4*)wqh; off = i - 1048576; }
    else                  { src = (const float4*)wp; dst = (f16x4*)wph; off = i - 1835008; }
    float4 v = src[off];
    f16x4 o = { (f16)v.x, (f16)v.y, (f16)v.z, (f16)v.w };
    dst[off] = o;
}

// ---------------------------------------------------------------- GEMM C = A @ B^T (m97 structure)
// (unchanged this round — need gemm counters before editing it)
template<int EPI>
__global__ __launch_bounds__(256) void gemm_k(
    const f16* __restrict__ A, const f16* __restrict__ B, int K,
    f16* __restrict__ qb, f16* __restrict__ kb, f16* __restrict__ vt,
    float* __restrict__ outF, const float* __restrict__ bias)
{
    __shared__ f16 as[128 * 32];
    __shared__ f16 bs[128 * 32];
    const int t = threadIdx.x;
    const int m0 = blockIdx.y * 128, n0 = blockIdx.x * 128;
    const int lane = t & 63, wv = t >> 6;
    const int wm = wv >> 1, wn = wv & 1;
    const int lr = lane & 15, g = lane >> 4;
    const int srow = lane >> 2, schk = (lane & 3) * 8;
    const f16* Ab = A + (size_t)m0 * K;
    const f16* Bb = B + (size_t)n0 * K;
    f32x4 acc[4][4] = {};

    for (int k0 = 0; k0 < K; k0 += 32) {
        __syncthreads();
        #pragma unroll
        for (int i2 = 0; i2 < 2; ++i2) {
            const int r0 = wv * 32 + i2 * 16;  // wave-uniform
            gld16(&Ab[(size_t)(r0 + srow) * K + k0 + schk], &as[r0 * 32]);
            gld16(&Bb[(size_t)(r0 + srow) * K + k0 + schk], &bs[r0 * 32]);
        }
        __syncthreads();
        f16x8 af[4], bf[4];
        #pragma unroll
        for (int mt = 0; mt < 4; ++mt)
            af[mt] = *reinterpret_cast<const f16x8*>(&as[(wm * 64 + mt * 16 + lr) * 32 + g * 8]);
        #pragma unroll
        for (int nt = 0; nt < 4; ++nt)
            bf[nt] = *reinterpret_cast<const f16x8*>(&bs[(wn * 64 + nt * 16 + lr) * 32 + g * 8]);
        #pragma unroll
        for (int mt = 0; mt < 4; ++mt)
            #pragma unroll
            for (int nt = 0; nt < 4; ++nt)
                acc[mt][nt] = MFMA16(af[mt], bf[nt], acc[mt][nt]);
    }

    #pragma unroll
    for (int mt = 0; mt < 4; ++mt) {
        #pragma unroll
        for (int nt = 0; nt < 4; ++nt) {
            const int n = n0 + wn * 64 + nt * 16 + lr;
            const int s0 = m0 + wm * 64 + mt * 16 + 4 * g;
            if (EPI == 0) {
                const int which = n >> 10, h = (n >> 6) & 15, d = n & 63;
                const int b = s0 >> 11, s = s0 & 2047;
                if (which == 2) {
                    f16x4 vv;
                    #pragma unroll
                    for (int i = 0; i < 4; ++i) vv[i] = (f16)acc[mt][nt][i];
                    *reinterpret_cast<f16x4*>(&vt[((size_t)((b << 4) + h) * 64 + d) * 2048 + s]) = vv;
                } else {
                    f16* dst = which ? kb : qb;
                    const float sc = which ? 1.0f : QSCALE;
                    #pragma unroll
                    for (int i = 0; i < 4; ++i)
                        dst[((size_t)((b << 4) + h) * 2048 + (s + i)) * 64 + d] = (f16)(acc[mt][nt][i] * sc);
                }
            } else {
                #pragma unroll
                for (int i = 0; i < 4; ++i)
                    outF[(size_t)(s0 + i) * 1024 + n] = acc[mt][nt][i] + bias[n];
            }
        }
    }
}

// ---------------------------------------------------------------- flash attention v4
// Uniform balanced flash-decoding. Each (bh, q-unit j) is split into nc(j) = ceil(ntt/11)
// balanced kv-chunks (nc = 1/2/3); every chunk is one 1-wave block writing a normalized
// partial (m, l, O/l f16). Grid 6144 (192 rest-slots x 32 bh; c >= nc exits). All chunks
// <= 11 tiles -> flat work distribution, short critical path. Swapped QK^T; KVB=64;
// Q pre-scaled by 8*log2(e) so scores are in exp2 domain.
__global__ __launch_bounds__(64) void attn_k(
    const f16* __restrict__ Q, const f16* __restrict__ K, const f16* __restrict__ VT,
    f16* __restrict__ opart, float* __restrict__ mpart, float* __restrict__ lpart)
{
    __shared__ f16 lp[32][72];
    const int lane = threadIdx.x;
    const int lr = lane & 15, g = lane >> 4;
    const int bid = blockIdx.x;
    const int bh = bid & 31;               // low bits -> stable XCD per bh (K/V L2 locality)
    const int rest = bid >> 5;             // 0..191, ordered j-desc (longest chunks first)
    const int j = 63 - rest / 3;
    const int c = rest % 3;
    const int ntt = (j >> 1) + 1;
    const int nc = unit_nc(j);
    if (c >= nc) return;
    const int cbase = ntt / nc, crem = ntt - cbase * nc;
    const int start = c * cbase + (c < crem ? c : crem);
    const int len = cbase + (c < crem ? 1 : 0);
    const bool diag = (start + len == ntt);

    const size_t base = (size_t)bh * (2048 * 64);
    const f16* Qb = Q + base;
    const f16* Kb = K + base;
    const f16* Vb = VT + base;             // [64][2048]
    const int q0 = j << 5;

    f16x8 qf[2][2];
    #pragma unroll
    for (int nt = 0; nt < 2; ++nt)
        #pragma unroll
        for (int ks = 0; ks < 2; ++ks)
            qf[nt][ks] = *reinterpret_cast<const f16x8*>(&Qb[(size_t)(q0 + nt * 16 + lr) * 64 + ks * 32 + g * 8]);

    f32x4 o[4][2] = {};
    float mrun[2] = { -1e30f, -1e30f };
    float lsum[2] = { 0.f, 0.f };          // per-lane partial; reduced once in epilogue

#define ATTN_TILE(KV0, MTMAX, MASKED) do {                                              \
    const int kv0_ = (KV0);                                                             \
    f32x4 st[MTMAX][2] = {};                                                            \
    _Pragma("unroll")                                                                   \
    for (int mt = 0; mt < MTMAX; ++mt) {                                                \
        f16x8 ak[2];                                                                    \
        _Pragma("unroll")                                                               \
        for (int ks = 0; ks < 2; ++ks)                                                  \
            ak[ks] = *reinterpret_cast<const f16x8*>(                                   \
                &Kb[(size_t)(kv0_ + mt * 16 + lr) * 64 + ks * 32 + g * 8]);             \
        _Pragma("unroll")                                                               \
        for (int nt = 0; nt < 2; ++nt)                                                  \
            _Pragma("unroll")                                                           \
            for (int ks = 0; ks < 2; ++ks)                                              \
                st[mt][nt] = MFMA16(ak[ks], qf[nt][ks], st[mt][nt]);                    \
    }                                                                                   \
    _Pragma("unroll")                                                                   \
    for (int nt = 0; nt < 2; ++nt) {                                                    \
        const int qrow_ = q0 + nt * 16 + lr;                                            \
        float mloc = -1e30f;                                                            \
        _Pragma("unroll")                                                               \
        for (int mt = 0; mt < MTMAX; ++mt)                                              \
            _Pragma("unroll")                                                           \
            for (int i = 0; i < 4; ++i) {                                               \
                float sv = st[mt][nt][i];                                               \
                if (MASKED) {                                                           \
                    int kkk = kv0_ + mt * 16 + 4 * g + i;                               \
                    sv = (kkk <= qrow_) ? sv : -1e30f;                                  \
                    st[mt][nt][i] = sv;                                                 \
                }                                                                       \
                mloc = fmaxf(mloc, sv);                                                 \
            }                                                                           \
        mloc = fmaxf(mloc, __shfl_xor(mloc, 16));                                       \
        mloc = fmaxf(mloc, __shfl_xor(mloc, 32));                                       \
        if (__any(mloc > mrun[nt] + 8.0f)) {       /* defer-max */                      \
            float mnew = fmaxf(mrun[nt], mloc);                                         \
            float sc = exp2f(mrun[nt] - mnew);                                          \
            lsum[nt] *= sc;                                                             \
            _Pragma("unroll")                                                           \
            for (int mo = 0; mo < 4; ++mo)                                              \
                _Pragma("unroll")                                                       \
                for (int i = 0; i < 4; ++i) o[mo][nt][i] *= sc;                         \
            mrun[nt] = mnew;                                                            \
        }                                                                               \
        float ls = 0.f;                                                                 \
        _Pragma("unroll")                                                               \
        for (int mt = 0; mt < MTMAX; ++mt) {                                            \
            f16x4 pk;                                                                   \
            _Pragma("unroll")                                                           \
            for (int i = 0; i < 4; ++i) {                                               \
                float p = exp2f(st[mt][nt][i] - mrun[nt]);                              \
                ls += p; pk[i] = (f16)p;                                                \
            }                                                                           \
            *reinterpret_cast<f16x4*>(&lp[nt * 16 + lr][mt * 16 + 4 * g]) = pk;         \
        }                                                                               \
        lsum[nt] += ls;                                                                 \
    }                                                                                   \
    {                                                                                   \
        constexpr int PVKS = (MTMAX) / 2;                                               \
        f16x8 pf[2][PVKS];                                                              \
        _Pragma("unroll")                                                               \
        for (int nt = 0; nt < 2; ++nt)                                                  \
            _Pragma("unroll")                                                           \
            for (int ks = 0; ks < PVKS; ++ks)                                           \
                pf[nt][ks] = *reinterpret_cast<const f16x8*>(                           \
                    &lp[nt * 16 + lr][ks * 32 + g * 8]);                                \
        _Pragma("unroll")                                                               \
        for (int mo = 0; mo < 4; ++mo) {                                                \
            f16x8 av[PVKS];                                                             \
            _Pragma("unroll")                                                           \
            for (int ks = 0; ks < PVKS; ++ks)                                           \
                av[ks] = *reinterpret_cast<const f16x8*>(                               \
                    &Vb[(size_t)(mo * 16 + lr) * 2048 + kv0_ + ks * 32 + g * 8]);       \
            _Pragma("unroll")                                                           \
            for (int nt = 0; nt < 2; ++nt)                                              \
                _Pragma("unroll")                                                       \
                for (int ks = 0; ks < PVKS; ++ks)                                       \
                    o[mo][nt] = MFMA16(av[ks], pf[nt][ks], o[mo][nt]);                  \
        }                                                                               \
    }                                                                                   \
} while (0)

    const int tEnd = start + len - (diag ? 1 : 0);
    for (int tt = start; tt < tEnd; ++tt)
        ATTN_TILE(tt << 6, 4, false);              // full tiles
    if (diag) {
        const int kvl = (ntt - 1) << 6;            // diagonal tile: masked
        if (j & 1) ATTN_TILE(kvl, 4, true);
        else       ATTN_TILE(kvl, 2, true);        // upper half fully masked
    }
#undef ATTN_TILE

    // epilogue: write normalized partial + (m, l) to slot
    const int slot = bh * 126 + unit_prefix(j) + c;
    #pragma unroll
    for (int nt = 0; nt < 2; ++nt) {
        float l = lsum[nt];
        l += __shfl_xor(l, 16);
        l += __shfl_xor(l, 32);
        const float inv = 1.0f / l;
        const int ql = nt * 16 + lr;               // local q (0..31)
        const int mi = slot * 32 + ql;
        #pragma unroll
        for (int mo = 0; mo < 4; ++mo) {
            f16x4 ov;
            #pragma unroll
            for (int i = 0; i < 4; ++i) ov[i] = (f16)(o[mo][nt][i] * inv);
            *reinterpret_cast<f16x4*>(&opart[(size_t)mi * 64 + mo * 16 + 4 * g]) = ov;
        }
        if (g == 0) { mpart[mi] = mrun[nt]; lpart[mi] = l; }
    }
}

// ---------------------------------------------------------------- combine partials -> ctx
// 2048 blocks = (bh 32) x (j 64); 256 threads: q = t>>3 (0..31), dc = (t&7)*8.
__global__ __launch_bounds__(256) void combine_k(
    const f16* __restrict__ opart, const float* __restrict__ mpart,
    const float* __restrict__ lpart, f16* __restrict__ ctx)
{
    const int blk = blockIdx.x;
    const int bh = blk & 31, j = blk >> 5;
    const int b = bh >> 4, h = bh & 15;
    const int nc = unit_nc(j);
    const int slot0 = bh * 126 + unit_prefix(j);
    const int t = threadIdx.x;
    const int q = t >> 3, dc = (t & 7) * 8;

    float m[3], l[3];
    float M = -1e30f;
    for (int cc = 0; cc < nc; ++cc) {
        m[cc] = mpart[(slot0 + cc) * 32 + q];
        l[cc] = lpart[(slot0 + cc) * 32 + q];
        M = fmaxf(M, m[cc]);
    }
    float wsum = 0.f, w[3];
    for (int cc = 0; cc < nc; ++cc) { w[cc] = l[cc] * exp2f(m[cc] - M); wsum += w[cc]; }
    const float r = 1.0f / wsum;

    float acc[8] = {};
    for (int cc = 0; cc < nc; ++cc) {
        const float coef = w[cc] * r;
        f16x8 v = *reinterpret_cast<const f16x8*>(&opart[(size_t)((slot0 + cc) * 32 + q) * 64 + dc]);
        #pragma unroll
        for (int i = 0; i < 8; ++i) acc[i] += coef * (float)v[i];
    }
    f16x8 outv;
    #pragma unroll
    for (int i = 0; i < 8; ++i) outv[i] = (f16)acc[i];
    const int qg = j * 32 + q;
    *reinterpret_cast<f16x8*>(&ctx[((size_t)(b * 2048 + qg)) * 1024 + h * 64 + dc]) = outv;
}

// ---------------------------------------------------------------- launch
extern "C" void kernel_launch(void* const* d_in, const int* in_sizes, int n_in,
                              void* d_out, int out_size, void* d_ws, size_t ws_size,
                              hipStream_t stream) {
    const float* x      = (const float*)d_in[0];   // [2,2048,1024]
    const float* w_qkv  = (const float*)d_in[1];   // [3072,1024]
    const float* w_proj = (const float*)d_in[2];   // [1024,1024]
    const float* b_proj = (const float*)d_in[3];   // [1024]
    float* out = (float*)d_out;                    // [2,2048,1024] fp32

    char* p = (char*)d_ws;
    f16* xh     = (f16*)p; p += (size_t)4096 * 1024 * 2;        // 8 MB (reused: m/l partials)
    f16* wqkvh  = (f16*)p; p += (size_t)3072 * 1024 * 2;        // 6 MB
    f16* wprojh = (f16*)p; p += (size_t)1024 * 1024 * 2;        // 2 MB (live through gemm1)
    f16* qbuf   = (f16*)p; p += (size_t)2 * 16 * 2048 * 64 * 2; // 8 MB  [B,H,S,64], pre-scaled
    f16* kbuf   = (f16*)p; p += (size_t)2 * 16 * 2048 * 64 * 2; // 8 MB  [B,H,S,64]
    f16* vtbuf  = (f16*)p; p += (size_t)2 * 16 * 64 * 2048 * 2; // 8 MB  [B,H,64,S] transposed
    f16* ctx    = (f16*)p; p += (size_t)4096 * 1024 * 2;        // 8 MB  (total 48 MB)

    // Partial O lives in d_out (dead until gemm1 overwrites it): 129024 rows x 128 B = 16.5 MB <= 16.78 MB.
    f16*   opart = (f16*)d_out;
    float* mpart = (float*)xh;               // 129024 f32 = 516 KB
    float* lpart = mpart + 129024;           // 129024 f32

    cvt_all<<<8192, 256, 0, stream>>>(x, w_qkv, w_proj, xh, wqkvh, wprojh);

    gemm_k<0><<<dim3(24, 32), 256, 0, stream>>>(xh, wqkvh, 1024, qbuf, kbuf, vtbuf, nullptr, nullptr);

    attn_k<<<6144, 64, 0, stream>>>(qbuf, kbuf, vtbuf, opart, mpart, lpart);

    combine_k<<<2048, 256, 0, stream>>>(opart, mpart, lpart, ctx);

    gemm_k<1><<<dim3(8, 32), 256, 0, stream>>>(ctx, wprojh, 1024, nullptr, nullptr, nullptr, out, b_proj);
}

// Round 6
// 199.508 us; speedup vs baseline: 1.2827x; 1.1135x over previous
//
#include <hip/hip_runtime.h>

typedef _Float16 f16;
typedef _Float16 f16x4 __attribute__((ext_vector_type(4)));
typedef _Float16 f16x8 __attribute__((ext_vector_type(8)));
typedef float f32x4 __attribute__((ext_vector_type(4)));

#define MFMA16(a, b, c) __builtin_amdgcn_mfma_f32_16x16x32_f16(a, b, c, 0, 0, 0)
#define QSCALE 11.5415603f   /* 8 * log2(e): folds the reference's x8 scale + exp2 domain */

typedef const __attribute__((address_space(1))) void* gp1_t;
typedef __attribute__((address_space(3))) void* lp3_t;
__device__ __forceinline__ void gld16(const void* g, void* l) {
    __builtin_amdgcn_global_load_lds((gp1_t)g, (lp3_t)l, 16, 0, 0);
}

// ---------------------------------------------------------------- fused fp32->fp16 converts
__global__ __launch_bounds__(256) void cvt_all(
    const float* __restrict__ x, const float* __restrict__ wq, const float* __restrict__ wp,
    f16* __restrict__ xh, f16* __restrict__ wqh, f16* __restrict__ wph)
{
    int i = blockIdx.x * 256 + threadIdx.x;          // float4 index, total 2097152 exact
    const float4* src; f16x4* dst; int off;
    if (i < 1048576)      { src = (const float4*)x;  dst = (f16x4*)xh;  off = i; }
    else if (i < 1835008) { src = (const float4*)wq; dst = (f16x4*)wqh; off = i - 1048576; }
    else                  { src = (const float4*)wp; dst = (f16x4*)wph; off = i - 1835008; }
    float4 v = src[off];
    f16x4 o = { (f16)v.x, (f16)v.y, (f16)v.z, (f16)v.w };
    dst[off] = o;
}

// ---------------------------------------------------------------- GEMM C = A @ B^T (m97 structure)
// (unchanged this round — gemm counters not yet surfaced)
template<int EPI>
__global__ __launch_bounds__(256) void gemm_k(
    const f16* __restrict__ A, const f16* __restrict__ B, int K,
    f16* __restrict__ qb, f16* __restrict__ kb, f16* __restrict__ vt,
    float* __restrict__ outF, const float* __restrict__ bias)
{
    __shared__ f16 as[128 * 32];
    __shared__ f16 bs[128 * 32];
    const int t = threadIdx.x;
    const int m0 = blockIdx.y * 128, n0 = blockIdx.x * 128;
    const int lane = t & 63, wv = t >> 6;
    const int wm = wv >> 1, wn = wv & 1;
    const int lr = lane & 15, g = lane >> 4;
    const int srow = lane >> 2, schk = (lane & 3) * 8;
    const f16* Ab = A + (size_t)m0 * K;
    const f16* Bb = B + (size_t)n0 * K;
    f32x4 acc[4][4] = {};

    for (int k0 = 0; k0 < K; k0 += 32) {
        __syncthreads();
        #pragma unroll
        for (int i2 = 0; i2 < 2; ++i2) {
            const int r0 = wv * 32 + i2 * 16;  // wave-uniform
            gld16(&Ab[(size_t)(r0 + srow) * K + k0 + schk], &as[r0 * 32]);
            gld16(&Bb[(size_t)(r0 + srow) * K + k0 + schk], &bs[r0 * 32]);
        }
        __syncthreads();
        f16x8 af[4], bf[4];
        #pragma unroll
        for (int mt = 0; mt < 4; ++mt)
            af[mt] = *reinterpret_cast<const f16x8*>(&as[(wm * 64 + mt * 16 + lr) * 32 + g * 8]);
        #pragma unroll
        for (int nt = 0; nt < 4; ++nt)
            bf[nt] = *reinterpret_cast<const f16x8*>(&bs[(wn * 64 + nt * 16 + lr) * 32 + g * 8]);
        #pragma unroll
        for (int mt = 0; mt < 4; ++mt)
            #pragma unroll
            for (int nt = 0; nt < 4; ++nt)
                acc[mt][nt] = MFMA16(af[mt], bf[nt], acc[mt][nt]);
    }

    #pragma unroll
    for (int mt = 0; mt < 4; ++mt) {
        #pragma unroll
        for (int nt = 0; nt < 4; ++nt) {
            const int n = n0 + wn * 64 + nt * 16 + lr;
            const int s0 = m0 + wm * 64 + mt * 16 + 4 * g;
            if (EPI == 0) {
                const int which = n >> 10, h = (n >> 6) & 15, d = n & 63;
                const int b = s0 >> 11, s = s0 & 2047;
                if (which == 2) {
                    f16x4 vv;
                    #pragma unroll
                    for (int i = 0; i < 4; ++i) vv[i] = (f16)acc[mt][nt][i];
                    *reinterpret_cast<f16x4*>(&vt[((size_t)((b << 4) + h) * 64 + d) * 2048 + s]) = vv;
                } else {
                    f16* dst = which ? kb : qb;
                    const float sc = which ? 1.0f : QSCALE;
                    #pragma unroll
                    for (int i = 0; i < 4; ++i)
                        dst[((size_t)((b << 4) + h) * 2048 + (s + i)) * 64 + d] = (f16)(acc[mt][nt][i] * sc);
                }
            } else {
                #pragma unroll
                for (int i = 0; i < 4; ++i)
                    outF[(size_t)(s0 + i) * 1024 + n] = acc[mt][nt][i] + bias[n];
            }
        }
    }
}

// ---------------------------------------------------------------- flash attention v5 (fat waves)
// QBLK=64 per wave: 4 independent 16-row softmax chains SHARE the same K/V tile loads
// (halves loads/MFMA, doubles in-wave ILP). 1-wave blocks, no barriers. Unit u (q rows
// [64u,64u+64)) has ntt=u+1 kv tiles, split into nc=ceil((u+1)/10) chunks (<=10 tiles).
// 68 chunks per bh x 32 bh = 2176 blocks. Split units (u>=10) write normalized partials
// (m,l,O/l f16); unsplit write ctx directly. Diagonal tile: triangular pruning.
__global__ __launch_bounds__(64, 2) void attn_k(
    const f16* __restrict__ Q, const f16* __restrict__ K, const f16* __restrict__ VT,
    f16* __restrict__ ctx, f16* __restrict__ opart,
    float* __restrict__ mpart, float* __restrict__ lpart)
{
    __shared__ f16 lp[64][72];
    const int lane = threadIdx.x;
    const int lr = lane & 15, g = lane >> 4;
    const int bid = blockIdx.x;
    const int bh = bid & 31;               // low bits -> stable XCD per bh (K/V L2 locality)
    const int rr = 67 - (bid >> 5);        // ascending chunk index; launch order = big-u first
    int u, c;
    if (rr < 10)      { u = rr;                 c = 0; }
    else if (rr < 30) { u = 10 + (rr - 10) / 2; c = (rr - 10) % 2; }
    else if (rr < 60) { u = 20 + (rr - 30) / 3; c = (rr - 30) % 3; }
    else              { u = 30 + (rr - 60) / 4; c = (rr - 60) % 4; }
    const int ntt = u + 1;
    const int nc  = 1 + u / 10;
    const int cbase = ntt / nc, crem = ntt % nc;
    const int start = c * cbase + (c < crem ? c : crem);
    const int len   = cbase + (c < crem ? 1 : 0);
    const bool diag = (start + len == ntt);

    const int b = bh >> 4, h = bh & 15;
    const size_t base = (size_t)bh * (2048 * 64);
    const f16* Qb = Q + base;
    const f16* Kb = K + base;
    const f16* Vb = VT + base;             // [64][2048]
    const int q0 = u << 6;

    f16x8 qf[4][2];
    #pragma unroll
    for (int nt = 0; nt < 4; ++nt)
        #pragma unroll
        for (int ks = 0; ks < 2; ++ks)
            qf[nt][ks] = *reinterpret_cast<const f16x8*>(&Qb[(size_t)(q0 + nt * 16 + lr) * 64 + ks * 32 + g * 8]);

    f32x4 o[4][4] = {};                    // o[mo(d)][nt(q)]
    float mrun[4] = { -1e30f, -1e30f, -1e30f, -1e30f };
    float lsum[4] = { 0.f, 0.f, 0.f, 0.f };

#define ATTN_TILE(KV0, DIAGM) do {                                                      \
    const int kv0_ = (KV0);                                                             \
    f32x4 st[4][4] = {};                                                                \
    _Pragma("unroll")                                                                   \
    for (int mt = 0; mt < 4; ++mt) {                                                    \
        f16x8 ak[2];                                                                    \
        _Pragma("unroll")                                                               \
        for (int ks = 0; ks < 2; ++ks)                                                  \
            ak[ks] = *reinterpret_cast<const f16x8*>(                                   \
                &Kb[(size_t)(kv0_ + mt * 16 + lr) * 64 + ks * 32 + g * 8]);             \
        _Pragma("unroll")                                                               \
        for (int nt = 0; nt < 4; ++nt)                                                  \
            if (!(DIAGM) || mt <= nt) {                                                 \
                _Pragma("unroll")                                                       \
                for (int ks = 0; ks < 2; ++ks)                                          \
                    st[mt][nt] = MFMA16(ak[ks], qf[nt][ks], st[mt][nt]);                \
            }                                                                           \
    }                                                                                   \
    _Pragma("unroll")                                                                   \
    for (int nt = 0; nt < 4; ++nt) {                                                    \
        float mloc = -1e30f;                                                            \
        _Pragma("unroll")                                                               \
        for (int mt = 0; mt < 4; ++mt) {                                                \
            if ((DIAGM) && mt > nt) continue;                                           \
            _Pragma("unroll")                                                           \
            for (int i = 0; i < 4; ++i) {                                               \
                float sv = st[mt][nt][i];                                               \
                if ((DIAGM) && mt == nt) {        /* kv0==q0: mask is 4g+i <= lr */     \
                    sv = (4 * g + i <= lr) ? sv : -1e30f;                               \
                    st[mt][nt][i] = sv;                                                 \
                }                                                                       \
                mloc = fmaxf(mloc, sv);                                                 \
            }                                                                           \
        }                                                                               \
        mloc = fmaxf(mloc, __shfl_xor(mloc, 16));                                       \
        mloc = fmaxf(mloc, __shfl_xor(mloc, 32));                                       \
        if (__any(mloc > mrun[nt] + 8.0f)) {       /* defer-max */                      \
            float mnew = fmaxf(mrun[nt], mloc);                                         \
            float sc = exp2f(mrun[nt] - mnew);                                          \
            lsum[nt] *= sc;                                                             \
            _Pragma("unroll")                                                           \
            for (int mo = 0; mo < 4; ++mo)                                              \
                _Pragma("unroll")                                                       \
                for (int i = 0; i < 4; ++i) o[mo][nt][i] *= sc;                         \
            mrun[nt] = mnew;                                                            \
        }                                                                               \
        float ls = 0.f;                                                                 \
        _Pragma("unroll")                                                               \
        for (int mt = 0; mt < 4; ++mt) {                                                \
            f16x4 pk;                                                                   \
            if ((DIAGM) && mt > nt) {                                                   \
                pk[0] = pk[1] = pk[2] = pk[3] = (f16)0.f;                               \
            } else {                                                                    \
                _Pragma("unroll")                                                       \
                for (int i = 0; i < 4; ++i) {                                           \
                    float p = exp2f(st[mt][nt][i] - mrun[nt]);                          \
                    ls += p; pk[i] = (f16)p;                                            \
                }                                                                       \
            }                                                                           \
            *reinterpret_cast<f16x4*>(&lp[nt * 16 + lr][mt * 16 + 4 * g]) = pk;         \
        }                                                                               \
        lsum[nt] += ls;                                                                 \
    }                                                                                   \
    {                                                                                   \
        f16x8 pf[4][2];                                                                 \
        _Pragma("unroll")                                                               \
        for (int nt = 0; nt < 4; ++nt)                                                  \
            _Pragma("unroll")                                                           \
            for (int ks = 0; ks < 2; ++ks)                                              \
                pf[nt][ks] = *reinterpret_cast<const f16x8*>(                           \
                    &lp[nt * 16 + lr][ks * 32 + g * 8]);                                \
        _Pragma("unroll")                                                               \
        for (int mo = 0; mo < 4; ++mo) {                                                \
            f16x8 av[2];                                                                \
            _Pragma("unroll")                                                           \
            for (int ks = 0; ks < 2; ++ks)                                              \
                av[ks] = *reinterpret_cast<const f16x8*>(                               \
                    &Vb[(size_t)(mo * 16 + lr) * 2048 + kv0_ + ks * 32 + g * 8]);       \
            _Pragma("unroll")                                                           \
            for (int nt = 0; nt < 4; ++nt)                                              \
                _Pragma("unroll")                                                       \
                for (int ks = 0; ks < 2; ++ks)                                          \
                    o[mo][nt] = MFMA16(av[ks], pf[nt][ks], o[mo][nt]);                  \
        }                                                                               \
    }                                                                                   \
} while (0)

    const int tEnd = start + len - (diag ? 1 : 0);
    for (int tt = start; tt < tEnd; ++tt)
        ATTN_TILE(tt << 6, 0);                     // full tiles
    if (diag)
        ATTN_TILE((ntt - 1) << 6, 1);              // diagonal tile, triangular
#undef ATTN_TILE

    // epilogue
    const bool split = (nc > 1);
    int slot = 0;
    if (split) {
        const int psl = (u < 20) ? 2 * (u - 10) : (u < 30 ? 20 + 3 * (u - 20) : 50 + 4 * (u - 30));
        slot = bh * 58 + psl + c;
    }
    #pragma unroll
    for (int nt = 0; nt < 4; ++nt) {
        float l = lsum[nt];
        l += __shfl_xor(l, 16);
        l += __shfl_xor(l, 32);
        const float inv = 1.0f / l;
        const int lrow = nt * 16 + lr;             // local q row (0..63)
        if (!split) {
            const size_t rowoff = ((size_t)(b * 2048 + q0 + lrow)) * 1024 + h * 64;
            #pragma unroll
            for (int mo = 0; mo < 4; ++mo) {
                f16x4 ov;
                #pragma unroll
                for (int i = 0; i < 4; ++i) ov[i] = (f16)(o[mo][nt][i] * inv);
                *reinterpret_cast<f16x4*>(&ctx[rowoff + mo * 16 + 4 * g]) = ov;
            }
        } else {
            const int mi = slot * 64 + lrow;
            #pragma unroll
            for (int mo = 0; mo < 4; ++mo) {
                f16x4 ov;
                #pragma unroll
                for (int i = 0; i < 4; ++i) ov[i] = (f16)(o[mo][nt][i] * inv);
                *reinterpret_cast<f16x4*>(&opart[(size_t)mi * 64 + mo * 16 + 4 * g]) = ov;
            }
            if (g == 0) { mpart[mi] = mrun[nt]; lpart[mi] = l; }
        }
    }
}

// ---------------------------------------------------------------- combine partials -> ctx
// 704 blocks = (bh 32) x (u-10: 22); 256 threads: lrow = t>>2 (0..63), seg = t&3 (16 f16).
__global__ __launch_bounds__(256) void combine_k(
    const f16* __restrict__ opart, const float* __restrict__ mpart,
    const float* __restrict__ lpart, f16* __restrict__ ctx)
{
    const int blk = blockIdx.x;
    const int bh = blk & 31, u = 10 + (blk >> 5);
    const int b = bh >> 4, h = bh & 15;
    const int nc = 1 + u / 10;                     // 2..4
    const int psl = (u < 20) ? 2 * (u - 10) : (u < 30 ? 20 + 3 * (u - 20) : 50 + 4 * (u - 30));
    const int slot0 = bh * 58 + psl;
    const int t = threadIdx.x;
    const int lrow = t >> 2, seg = t & 3;

    float m[4], l[4], w[4];
    float M = -1e30f;
    #pragma unroll 4
    for (int cc = 0; cc < 4; ++cc) if (cc < nc) {
        m[cc] = mpart[(slot0 + cc) * 64 + lrow];
        l[cc] = lpart[(slot0 + cc) * 64 + lrow];
        M = fmaxf(M, m[cc]);
    }
    float wsum = 0.f;
    #pragma unroll 4
    for (int cc = 0; cc < 4; ++cc) if (cc < nc) { w[cc] = l[cc] * exp2f(m[cc] - M); wsum += w[cc]; }
    const float r = 1.0f / wsum;

    float acc[16] = {};
    #pragma unroll 4
    for (int cc = 0; cc < 4; ++cc) if (cc < nc) {
        const float coef = w[cc] * r;
        const size_t rb = (size_t)((slot0 + cc) * 64 + lrow) * 64 + seg * 16;
        f16x8 v0 = *reinterpret_cast<const f16x8*>(&opart[rb]);
        f16x8 v1 = *reinterpret_cast<const f16x8*>(&opart[rb + 8]);
        #pragma unroll
        for (int i = 0; i < 8; ++i) { acc[i] += coef * (float)v0[i]; acc[i + 8] += coef * (float)v1[i]; }
    }
    f16x8 o0, o1;
    #pragma unroll
    for (int i = 0; i < 8; ++i) { o0[i] = (f16)acc[i]; o1[i] = (f16)acc[i + 8]; }
    const size_t wb = ((size_t)(b * 2048 + u * 64 + lrow)) * 1024 + h * 64 + seg * 16;
    *reinterpret_cast<f16x8*>(&ctx[wb]) = o0;
    *reinterpret_cast<f16x8*>(&ctx[wb + 8]) = o1;
}

// ---------------------------------------------------------------- launch
extern "C" void kernel_launch(void* const* d_in, const int* in_sizes, int n_in,
                              void* d_out, int out_size, void* d_ws, size_t ws_size,
                              hipStream_t stream) {
    const float* x      = (const float*)d_in[0];   // [2,2048,1024]
    const float* w_qkv  = (const float*)d_in[1];   // [3072,1024]
    const float* w_proj = (const float*)d_in[2];   // [1024,1024]
    const float* b_proj = (const float*)d_in[3];   // [1024]
    float* out = (float*)d_out;                    // [2,2048,1024] fp32

    char* p = (char*)d_ws;
    f16* xh     = (f16*)p; p += (size_t)4096 * 1024 * 2;        // 8 MB (reused: m/l partials)
    f16* wqkvh  = (f16*)p; p += (size_t)3072 * 1024 * 2;        // 6 MB
    f16* wprojh = (f16*)p; p += (size_t)1024 * 1024 * 2;        // 2 MB (live through gemm1)
    f16* qbuf   = (f16*)p; p += (size_t)2 * 16 * 2048 * 64 * 2; // 8 MB  [B,H,S,64], pre-scaled
    f16* kbuf   = (f16*)p; p += (size_t)2 * 16 * 2048 * 64 * 2; // 8 MB  [B,H,S,64]
    f16* vtbuf  = (f16*)p; p += (size_t)2 * 16 * 64 * 2048 * 2; // 8 MB  [B,H,64,S] transposed
    f16* ctx    = (f16*)p; p += (size_t)4096 * 1024 * 2;        // 8 MB  (total 48 MB)

    // Partial O lives in d_out (dead until gemm1 overwrites it):
    // 58 slots x 32 bh x 64 rows x 128 B = 15.2 MB <= 16.78 MB.
    f16*   opart = (f16*)d_out;
    float* mpart = (float*)xh;               // 118784 f32
    float* lpart = mpart + 118784;           // 118784 f32

    cvt_all<<<8192, 256, 0, stream>>>(x, w_qkv, w_proj, xh, wqkvh, wprojh);

    gemm_k<0><<<dim3(24, 32), 256, 0, stream>>>(xh, wqkvh, 1024, qbuf, kbuf, vtbuf, nullptr, nullptr);

    attn_k<<<2176, 64, 0, stream>>>(qbuf, kbuf, vtbuf, ctx, opart, mpart, lpart);

    combine_k<<<704, 256, 0, stream>>>(opart, mpart, lpart, ctx);

    gemm_k<1><<<dim3(8, 32), 256, 0, stream>>>(ctx, wprojh, 1024, nullptr, nullptr, nullptr, out, b_proj);
}

// Round 7
// 196.430 us; speedup vs baseline: 1.3028x; 1.0157x over previous
//
#include <hip/hip_runtime.h>

typedef _Float16 f16;
typedef _Float16 f16x4 __attribute__((ext_vector_type(4)));
typedef _Float16 f16x8 __attribute__((ext_vector_type(8)));
typedef float f32x4 __attribute__((ext_vector_type(4)));

#define MFMA16(a, b, c) __builtin_amdgcn_mfma_f32_16x16x32_f16(a, b, c, 0, 0, 0)
#define QSCALE 11.5415603f   /* 8 * log2(e): folds the reference's x8 scale + exp2 domain */

typedef const __attribute__((address_space(1))) void* gp1_t;
typedef __attribute__((address_space(3))) void* lp3_t;
__device__ __forceinline__ void gld16(const void* g, void* l) {
    __builtin_amdgcn_global_load_lds((gp1_t)g, (lp3_t)l, 16, 0, 0);
}

// ---------------------------------------------------------------- fused fp32->fp16 converts
__global__ __launch_bounds__(256) void cvt_all(
    const float* __restrict__ x, const float* __restrict__ wq, const float* __restrict__ wp,
    f16* __restrict__ xh, f16* __restrict__ wqh, f16* __restrict__ wph)
{
    int i = blockIdx.x * 256 + threadIdx.x;          // float4 index, total 2097152 exact
    const float4* src; f16x4* dst; int off;
    if (i < 1048576)      { src = (const float4*)x;  dst = (f16x4*)xh;  off = i; }
    else if (i < 1835008) { src = (const float4*)wq; dst = (f16x4*)wqh; off = i - 1048576; }
    else                  { src = (const float4*)wp; dst = (f16x4*)wph; off = i - 1835008; }
    float4 v = src[off];
    f16x4 o = { (f16)v.x, (f16)v.y, (f16)v.z, (f16)v.w };
    dst[off] = o;
}

// ---------------------------------------------------------------- GEMM C = A @ B^T (m97 structure)
// A [M][K], B [N][K] f16 row-major. BM=128, BN in {128,64}. 4 waves 2x2; BK=32; linear LDS;
// global_load_lds width-16 staging; bijective XCD swizzle (grid divisible by 8).
// EPI 0 (BN=128): scatter Q(*QSCALE)/K into [B,H,S,64], V transposed into [B,H,64,S]
// EPI 1 (BN=64):  out fp32 [M][1024] + bias   (512 blocks -> 2 blocks/CU)
template<int EPI, int BN>
__global__ __launch_bounds__(256) void gemm_k(
    const f16* __restrict__ A, const f16* __restrict__ B, int K,
    f16* __restrict__ qb, f16* __restrict__ kb, f16* __restrict__ vt,
    float* __restrict__ outF, const float* __restrict__ bias)
{
    __shared__ f16 as[128 * 32];
    __shared__ f16 bs[BN * 32];
    constexpr int WN = BN / 2;        // wave n-extent
    constexpr int NT = BN / 32;       // n frags per wave
    const int t = threadIdx.x;
    // bijective XCD swizzle (nwg % 8 == 0 for both grids)
    const int bidf = blockIdx.y * gridDim.x + blockIdx.x;
    const int cpx  = (gridDim.x * gridDim.y) >> 3;
    const int swz  = (bidf & 7) * cpx + (bidf >> 3);
    const int m0 = (swz / gridDim.x) * 128, n0 = (swz % gridDim.x) * BN;
    const int lane = t & 63, wv = t >> 6;
    const int wm = wv >> 1, wn = wv & 1;
    const int lr = lane & 15, g = lane >> 4;
    const int srow = lane >> 2, schk = (lane & 3) * 8;   // 16 rows x 4 chunks of 16B per instr
    const f16* Ab = A + (size_t)m0 * K;
    const f16* Bb = B + (size_t)n0 * K;
    f32x4 acc[4][NT] = {};

    for (int k0 = 0; k0 < K; k0 += 32) {
        __syncthreads();
        #pragma unroll
        for (int i2 = 0; i2 < 2; ++i2) {
            const int r0 = wv * 32 + i2 * 16;  // wave-uniform
            gld16(&Ab[(size_t)(r0 + srow) * K + k0 + schk], &as[r0 * 32]);
        }
        if constexpr (BN == 128) {
            #pragma unroll
            for (int i2 = 0; i2 < 2; ++i2) {
                const int r0 = wv * 32 + i2 * 16;
                gld16(&Bb[(size_t)(r0 + srow) * K + k0 + schk], &bs[r0 * 32]);
            }
        } else {
            const int r0 = wv * 16;
            gld16(&Bb[(size_t)(r0 + srow) * K + k0 + schk], &bs[r0 * 32]);
        }
        __syncthreads();                       // compiler drains vmcnt before barrier
        f16x8 af[4], bf[NT];
        #pragma unroll
        for (int mt = 0; mt < 4; ++mt)
            af[mt] = *reinterpret_cast<const f16x8*>(&as[(wm * 64 + mt * 16 + lr) * 32 + g * 8]);
        #pragma unroll
        for (int nt = 0; nt < NT; ++nt)
            bf[nt] = *reinterpret_cast<const f16x8*>(&bs[(wn * WN + nt * 16 + lr) * 32 + g * 8]);
        #pragma unroll
        for (int mt = 0; mt < 4; ++mt)
            #pragma unroll
            for (int nt = 0; nt < NT; ++nt)
                acc[mt][nt] = MFMA16(af[mt], bf[nt], acc[mt][nt]);
    }

    // C/D layout: col = lane&15 (n), row = 4*(lane>>4)+i (m)
    #pragma unroll
    for (int mt = 0; mt < 4; ++mt) {
        #pragma unroll
        for (int nt = 0; nt < NT; ++nt) {
            const int n = n0 + wn * WN + nt * 16 + lr;
            const int s0 = m0 + wm * 64 + mt * 16 + 4 * g;
            if (EPI == 0) {
                const int which = n >> 10, h = (n >> 6) & 15, d = n & 63;
                const int b = s0 >> 11, s = s0 & 2047;
                if (which == 2) {
                    f16x4 vv;
                    #pragma unroll
                    for (int i = 0; i < 4; ++i) vv[i] = (f16)acc[mt][nt][i];
                    *reinterpret_cast<f16x4*>(&vt[((size_t)((b << 4) + h) * 64 + d) * 2048 + s]) = vv;
                } else {
                    f16* dst = which ? kb : qb;
                    const float sc = which ? 1.0f : QSCALE;
                    #pragma unroll
                    for (int i = 0; i < 4; ++i)
                        dst[((size_t)((b << 4) + h) * 2048 + (s + i)) * 64 + d] = (f16)(acc[mt][nt][i] * sc);
                }
            } else {
                #pragma unroll
                for (int i = 0; i < 4; ++i)
                    outF[(size_t)(s0 + i) * 1024 + n] = acc[mt][nt][i] + bias[n];
            }
        }
    }
}

// ---------------------------------------------------------------- flash attention v6
// v5 fat-wave structure + register double-buffered K prefetch: tile i+1's K-frag loads
// issue before tile i's softmax/PV, hiding the ~200-cyc L2 latency under compute.
// Named akA/akB buffers + unroll-2 loop keep all indexing compile-time (no scratch).
__global__ __launch_bounds__(64, 2) void attn_k(
    const f16* __restrict__ Q, const f16* __restrict__ K, const f16* __restrict__ VT,
    f16* __restrict__ ctx, f16* __restrict__ opart,
    float* __restrict__ mpart, float* __restrict__ lpart)
{
    __shared__ f16 lp[64][72];
    const int lane = threadIdx.x;
    const int lr = lane & 15, g = lane >> 4;
    const int bid = blockIdx.x;
    const int bh = bid & 31;               // low bits -> stable XCD per bh (K/V L2 locality)
    const int rr = 67 - (bid >> 5);        // ascending chunk index; launch order = big-u first
    int u, c;
    if (rr < 10)      { u = rr;                 c = 0; }
    else if (rr < 30) { u = 10 + (rr - 10) / 2; c = (rr - 10) % 2; }
    else if (rr < 60) { u = 20 + (rr - 30) / 3; c = (rr - 30) % 3; }
    else              { u = 30 + (rr - 60) / 4; c = (rr - 60) % 4; }
    const int ntt = u + 1;
    const int nc  = 1 + u / 10;
    const int cbase = ntt / nc, crem = ntt % nc;
    const int start = c * cbase + (c < crem ? c : crem);
    const int len   = cbase + (c < crem ? 1 : 0);
    const bool diag = (start + len == ntt);

    const int b = bh >> 4, h = bh & 15;
    const size_t base = (size_t)bh * (2048 * 64);
    const f16* Qb = Q + base;
    const f16* Kb = K + base;
    const f16* Vb = VT + base;             // [64][2048]
    const int q0 = u << 6;

    f16x8 qf[4][2];
    #pragma unroll
    for (int nt = 0; nt < 4; ++nt)
        #pragma unroll
        for (int ks = 0; ks < 2; ++ks)
            qf[nt][ks] = *reinterpret_cast<const f16x8*>(&Qb[(size_t)(q0 + nt * 16 + lr) * 64 + ks * 32 + g * 8]);

    f32x4 o[4][4] = {};                    // o[mo(d)][nt(q)]
    float mrun[4] = { -1e30f, -1e30f, -1e30f, -1e30f };
    float lsum[4] = { 0.f, 0.f, 0.f, 0.f };
    f16x8 akA[4][2], akB[4][2];

#define LOADK(BUF, I) do {                                                              \
    const int kvL_ = (start + (I)) << 6;                                                \
    _Pragma("unroll")                                                                   \
    for (int mt = 0; mt < 4; ++mt)                                                      \
        _Pragma("unroll")                                                               \
        for (int ks = 0; ks < 2; ++ks)                                                  \
            BUF[mt][ks] = *reinterpret_cast<const f16x8*>(                              \
                &Kb[(size_t)(kvL_ + mt * 16 + lr) * 64 + ks * 32 + g * 8]);             \
} while (0)

#define TILE_BODY(BUF, I, DIAGM) do {                                                   \
    const int kv0_ = (start + (I)) << 6;                                                \
    f32x4 st[4][4] = {};                                                                \
    _Pragma("unroll")                                                                   \
    for (int mt = 0; mt < 4; ++mt)                                                      \
        _Pragma("unroll")                                                               \
        for (int nt = 0; nt < 4; ++nt)                                                  \
            if (!(DIAGM) || mt <= nt) {                                                 \
                _Pragma("unroll")                                                       \
                for (int ks = 0; ks < 2; ++ks)                                          \
                    st[mt][nt] = MFMA16(BUF[mt][ks], qf[nt][ks], st[mt][nt]);           \
            }                                                                           \
    _Pragma("unroll")                                                                   \
    for (int nt = 0; nt < 4; ++nt) {                                                    \
        float mloc = -1e30f;                                                            \
        _Pragma("unroll")                                                               \
        for (int mt = 0; mt < 4; ++mt) {                                                \
            if ((DIAGM) && mt > nt) continue;                                           \
            _Pragma("unroll")                                                           \
            for (int i = 0; i < 4; ++i) {                                               \
                float sv = st[mt][nt][i];                                               \
                if ((DIAGM) && mt == nt) {        /* kv0==q-row block: mask 4g+i<=lr */ \
                    sv = (4 * g + i <= lr) ? sv : -1e30f;                               \
                    st[mt][nt][i] = sv;                                                 \
                }                                                                       \
                mloc = fmaxf(mloc, sv);                                                 \
            }                                                                           \
        }                                                                               \
        mloc = fmaxf(mloc, __shfl_xor(mloc, 16));                                       \
        mloc = fmaxf(mloc, __shfl_xor(mloc, 32));                                       \
        if (__any(mloc > mrun[nt] + 8.0f)) {       /* defer-max */                      \
            float mnew = fmaxf(mrun[nt], mloc);                                         \
            float sc = exp2f(mrun[nt] - mnew);                                          \
            lsum[nt] *= sc;                                                             \
            _Pragma("unroll")                                                           \
            for (int mo = 0; mo < 4; ++mo)                                              \
                _Pragma("unroll")                                                       \
                for (int i = 0; i < 4; ++i) o[mo][nt][i] *= sc;                         \
            mrun[nt] = mnew;                                                            \
        }                                                                               \
        float ls = 0.f;                                                                 \
        _Pragma("unroll")                                                               \
        for (int mt = 0; mt < 4; ++mt) {                                                \
            f16x4 pk;                                                                   \
            if ((DIAGM) && mt > nt) {                                                   \
                pk[0] = pk[1] = pk[2] = pk[3] = (f16)0.f;                               \
            } else {                                                                    \
                _Pragma("unroll")                                                       \
                for (int i = 0; i < 4; ++i) {                                           \
                    float p = exp2f(st[mt][nt][i] - mrun[nt]);                          \
                    ls += p; pk[i] = (f16)p;                                            \
                }                                                                       \
            }                                                                           \
            *reinterpret_cast<f16x4*>(&lp[nt * 16 + lr][mt * 16 + 4 * g]) = pk;         \
        }                                                                               \
        lsum[nt] += ls;                                                                 \
    }                                                                                   \
    {                                                                                   \
        f16x8 pf[4][2];                                                                 \
        _Pragma("unroll")                                                               \
        for (int nt = 0; nt < 4; ++nt)                                                  \
            _Pragma("unroll")                                                           \
            for (int ks = 0; ks < 2; ++ks)                                              \
                pf[nt][ks] = *reinterpret_cast<const f16x8*>(                           \
                    &lp[nt * 16 + lr][ks * 32 + g * 8]);                                \
        _Pragma("unroll")                                                               \
        for (int mo = 0; mo < 4; ++mo) {                                                \
            f16x8 av[2];                                                                \
            _Pragma("unroll")                                                           \
            for (int ks = 0; ks < 2; ++ks)                                              \
                av[ks] = *reinterpret_cast<const f16x8*>(                               \
                    &Vb[(size_t)(mo * 16 + lr) * 2048 + kv0_ + ks * 32 + g * 8]);       \
            _Pragma("unroll")                                                           \
            for (int nt = 0; nt < 4; ++nt)                                              \
                _Pragma("unroll")                                                       \
                for (int ks = 0; ks < 2; ++ks)                                          \
                    o[mo][nt] = MFMA16(av[ks], pf[nt][ks], o[mo][nt]);                  \
        }                                                                               \
    }                                                                                   \
} while (0)

    // software pipeline: tiles i = 0..len-1 (kv = (start+i)*64); last is masked iff diag.
    const int nfull = len - (diag ? 1 : 0);
    LOADK(akA, 0);
    int i = 0;
    for (; i + 2 <= nfull; i += 2) {
        LOADK(akB, i + 1);
        TILE_BODY(akA, i, 0);
        if (i + 2 < len) LOADK(akA, i + 2);
        TILE_BODY(akB, i + 1, 0);
    }
    if (i < nfull) {                       // one full tile left, in akA
        if (diag) {
            LOADK(akB, i + 1);
            TILE_BODY(akA, i, 0);
            TILE_BODY(akB, i + 1, 1);
        } else {
            TILE_BODY(akA, i, 0);
        }
    } else if (diag) {
        TILE_BODY(akA, nfull, 1);          // diag tile already prefetched into akA
    }
#undef LOADK
#undef TILE_BODY

    // epilogue
    const bool split = (nc > 1);
    int slot = 0;
    if (split) {
        const int psl = (u < 20) ? 2 * (u - 10) : (u < 30 ? 20 + 3 * (u - 20) : 50 + 4 * (u - 30));
        slot = bh * 58 + psl + c;
    }
    #pragma unroll
    for (int nt = 0; nt < 4; ++nt) {
        float l = lsum[nt];
        l += __shfl_xor(l, 16);
        l += __shfl_xor(l, 32);
        const float inv = 1.0f / l;
        const int lrow = nt * 16 + lr;             // local q row (0..63)
        if (!split) {
            const size_t rowoff = ((size_t)(b * 2048 + q0 + lrow)) * 1024 + h * 64;
            #pragma unroll
            for (int mo = 0; mo < 4; ++mo) {
                f16x4 ov;
                #pragma unroll
                for (int i2 = 0; i2 < 4; ++i2) ov[i2] = (f16)(o[mo][nt][i2] * inv);
                *reinterpret_cast<f16x4*>(&ctx[rowoff + mo * 16 + 4 * g]) = ov;
            }
        } else {
            const int mi = slot * 64 + lrow;
            #pragma unroll
            for (int mo = 0; mo < 4; ++mo) {
                f16x4 ov;
                #pragma unroll
                for (int i2 = 0; i2 < 4; ++i2) ov[i2] = (f16)(o[mo][nt][i2] * inv);
                *reinterpret_cast<f16x4*>(&opart[(size_t)mi * 64 + mo * 16 + 4 * g]) = ov;
            }
            if (g == 0) { mpart[mi] = mrun[nt]; lpart[mi] = l; }
        }
    }
}

// ---------------------------------------------------------------- combine partials -> ctx
// 704 blocks = (bh 32) x (u-10: 22); 256 threads: lrow = t>>2 (0..63), seg = t&3 (16 f16).
__global__ __launch_bounds__(256) void combine_k(
    const f16* __restrict__ opart, const float* __restrict__ mpart,
    const float* __restrict__ lpart, f16* __restrict__ ctx)
{
    const int blk = blockIdx.x;
    const int bh = blk & 31, u = 10 + (blk >> 5);
    const int b = bh >> 4, h = bh & 15;
    const int nc = 1 + u / 10;                     // 2..4
    const int psl = (u < 20) ? 2 * (u - 10) : (u < 30 ? 20 + 3 * (u - 20) : 50 + 4 * (u - 30));
    const int slot0 = bh * 58 + psl;
    const int t = threadIdx.x;
    const int lrow = t >> 2, seg = t & 3;

    float m[4], l[4], w[4];
    float M = -1e30f;
    #pragma unroll 4
    for (int cc = 0; cc < 4; ++cc) if (cc < nc) {
        m[cc] = mpart[(slot0 + cc) * 64 + lrow];
        l[cc] = lpart[(slot0 + cc) * 64 + lrow];
        M = fmaxf(M, m[cc]);
    }
    float wsum = 0.f;
    #pragma unroll 4
    for (int cc = 0; cc < 4; ++cc) if (cc < nc) { w[cc] = l[cc] * exp2f(m[cc] - M); wsum += w[cc]; }
    const float r = 1.0f / wsum;

    float acc[16] = {};
    #pragma unroll 4
    for (int cc = 0; cc < 4; ++cc) if (cc < nc) {
        const float coef = w[cc] * r;
        const size_t rb = (size_t)((slot0 + cc) * 64 + lrow) * 64 + seg * 16;
        f16x8 v0 = *reinterpret_cast<const f16x8*>(&opart[rb]);
        f16x8 v1 = *reinterpret_cast<const f16x8*>(&opart[rb + 8]);
        #pragma unroll
        for (int i = 0; i < 8; ++i) { acc[i] += coef * (float)v0[i]; acc[i + 8] += coef * (float)v1[i]; }
    }
    f16x8 o0, o1;
    #pragma unroll
    for (int i = 0; i < 8; ++i) { o0[i] = (f16)acc[i]; o1[i] = (f16)acc[i + 8]; }
    const size_t wb = ((size_t)(b * 2048 + u * 64 + lrow)) * 1024 + h * 64 + seg * 16;
    *reinterpret_cast<f16x8*>(&ctx[wb]) = o0;
    *reinterpret_cast<f16x8*>(&ctx[wb + 8]) = o1;
}

// ---------------------------------------------------------------- launch
extern "C" void kernel_launch(void* const* d_in, const int* in_sizes, int n_in,
                              void* d_out, int out_size, void* d_ws, size_t ws_size,
                              hipStream_t stream) {
    const float* x      = (const float*)d_in[0];   // [2,2048,1024]
    const float* w_qkv  = (const float*)d_in[1];   // [3072,1024]
    const float* w_proj = (const float*)d_in[2];   // [1024,1024]
    const float* b_proj = (const float*)d_in[3];   // [1024]
    float* out = (float*)d_out;                    // [2,2048,1024] fp32

    char* p = (char*)d_ws;
    f16* xh     = (f16*)p; p += (size_t)4096 * 1024 * 2;        // 8 MB (reused: m/l partials)
    f16* wqkvh  = (f16*)p; p += (size_t)3072 * 1024 * 2;        // 6 MB
    f16* wprojh = (f16*)p; p += (size_t)1024 * 1024 * 2;        // 2 MB (live through gemm1)
    f16* qbuf   = (f16*)p; p += (size_t)2 * 16 * 2048 * 64 * 2; // 8 MB  [B,H,S,64], pre-scaled
    f16* kbuf   = (f16*)p; p += (size_t)2 * 16 * 2048 * 64 * 2; // 8 MB  [B,H,S,64]
    f16* vtbuf  = (f16*)p; p += (size_t)2 * 16 * 64 * 2048 * 2; // 8 MB  [B,H,64,S] transposed
    f16* ctx    = (f16*)p; p += (size_t)4096 * 1024 * 2;        // 8 MB  (total 48 MB)

    // Partial O lives in d_out (dead until gemm1 overwrites it):
    // 58 slots x 32 bh x 64 rows x 128 B = 15.2 MB <= 16.78 MB.
    f16*   opart = (f16*)d_out;
    float* mpart = (float*)xh;               // 118784 f32
    float* lpart = mpart + 118784;           // 118784 f32

    cvt_all<<<8192, 256, 0, stream>>>(x, w_qkv, w_proj, xh, wqkvh, wprojh);

    gemm_k<0, 128><<<dim3(24, 32), 256, 0, stream>>>(xh, wqkvh, 1024, qbuf, kbuf, vtbuf, nullptr, nullptr);

    attn_k<<<2176, 64, 0, stream>>>(qbuf, kbuf, vtbuf, ctx, opart, mpart, lpart);

    combine_k<<<704, 256, 0, stream>>>(opart, mpart, lpart, ctx);

    gemm_k<1, 64><<<dim3(16, 32), 256, 0, stream>>>(ctx, wprojh, 1024, nullptr, nullptr, nullptr, out, b_proj);
}